// Round 6
// baseline (938.764 us; speedup 1.0000x reference)
//
#include <hip/hip_runtime.h>
#include <math.h>

#define N_USERS 50000
#define N_ITEMS 30000
#define N_ENTITIES 80000
#define N_UI (N_USERS + N_ITEMS)
#define D 64
#define N_KG_EDGES 2000000
#define N_INTERACT 1000000
#define N_ADJ 2000000
#define INV_TEMP 5.0f
#define EPS_PD 1e-6f
#define SCAN_T 1024
#define NPASS 8
#define CSLOTS 6   // LDS-cached rows per 16-lane group in user_hop

typedef _Float16 f16;

__device__ __forceinline__ float4 ld_h4(const f16* p) {
    struct h4 { f16 x, y, z, w; };
    h4 h = *(const h4*)p;
    return make_float4((float)h.x, (float)h.y, (float)h.z, (float)h.w);
}

__device__ __forceinline__ void st_h4(f16* p, float4 v) {
    struct h4 { f16 x, y, z, w; };
    h4 h = {(f16)v.x, (f16)v.y, (f16)v.z, (f16)v.w};
    *(h4*)p = h;
}

// ---- int histogram ----
__global__ void hist_kernel(const int* __restrict__ keys, int* __restrict__ cnt, int n) {
    int e = blockIdx.x * blockDim.x + threadIdx.x;
    if (e < n) atomicAdd(&cnt[keys[e]], 1);
}

// ---- icnt = 1/max(cnt,1) ----
__global__ void icnt_kernel(const int* __restrict__ cnt, float* __restrict__ icnt) {
    int i = blockIdx.x * blockDim.x + threadIdx.x;
    if (i < N_ENTITIES) icnt[i] = 1.0f / fmaxf((float)cnt[i], 1.0f);
}

// ---- fp32 -> fp16 bulk convert (4 elems/thread) ----
__global__ void cvt16_kernel(const float* __restrict__ in, f16* __restrict__ outp, int n4) {
    int i = blockIdx.x * blockDim.x + threadIdx.x;
    if (i < n4) st_h4(outp + (size_t)i * 4, *(const float4*)(in + (size_t)i * 4));
}

// ---- single-block scan; writes rowptr (exclusive+1) AND pos (exclusive) ----
__global__ void scan_kernel(const int* __restrict__ cnt, int* __restrict__ rowptr,
                            int* __restrict__ pos, int n) {
    __shared__ int wpart[16];
    __shared__ int carry_s;
    int lane = threadIdx.x & 63;
    int wv = threadIdx.x >> 6;
    if (threadIdx.x == 0) { carry_s = 0; rowptr[0] = 0; }
    __syncthreads();
    for (int base = 0; base < n; base += SCAN_T) {
        int i = base + threadIdx.x;
        int v = (i < n) ? cnt[i] : 0;
        int x = v;
        #pragma unroll
        for (int o = 1; o < 64; o <<= 1) {
            int t = __shfl_up(x, o, 64);
            if (lane >= o) x += t;
        }
        if (lane == 63) wpart[wv] = x;
        __syncthreads();
        if (wv == 0) {
            int p = (lane < 16) ? wpart[lane] : 0;
            #pragma unroll
            for (int o = 1; o < 16; o <<= 1) {
                int t = __shfl_up(p, o, 64);
                if (lane >= o) p += t;
            }
            if (lane < 16) wpart[lane] = p;
        }
        __syncthreads();
        int add = carry_s + (wv > 0 ? wpart[wv - 1] : 0);
        int incl = x + add;
        if (i < n) { rowptr[i + 1] = incl; pos[i] = incl - v; }
        __syncthreads();
        if (threadIdx.x == SCAN_T - 1) carry_s = incl;
        __syncthreads();
    }
}

// ---- KG fill, 8-pass sliced, nontemporal scatter stores ----
__global__ void kg_fill(const int* __restrict__ edge_index, int* __restrict__ pos,
                        int* __restrict__ tails) {
    int pass = blockIdx.x & (NPASS - 1);
    int e = (blockIdx.x >> 3) * blockDim.x + threadIdx.x;
    if (e >= N_KG_EDGES) return;
    int h = edge_index[e];
    if ((unsigned)(h - pass * (N_ENTITIES / NPASS)) >= (unsigned)(N_ENTITIES / NPASS)) return;
    int slot = atomicAdd(&pos[h], 1);
    __builtin_nontemporal_store(edge_index[N_KG_EDGES + e], &tails[slot]);
}

// ---- adj fill, 8-pass sliced, fused (col,val) 8B nontemporal stores ----
__global__ void adj_fill(const int* __restrict__ rows, const int* __restrict__ cols,
                         const float* __restrict__ vals, int* __restrict__ pos,
                         int2* __restrict__ pair) {
    int pass = blockIdx.x & (NPASS - 1);
    int e = (blockIdx.x >> 3) * blockDim.x + threadIdx.x;
    if (e >= N_ADJ) return;
    int r = rows[e];
    if ((unsigned)(r - pass * (N_UI / NPASS)) >= (unsigned)(N_UI / NPASS)) return;
    int slot = atomicAdd(&pos[r], 1);
    unsigned long long v = (unsigned long long)(unsigned)cols[e] |
                           ((unsigned long long)__float_as_uint(vals[e]) << 32);
    __builtin_nontemporal_store(v, (unsigned long long*)&pair[slot]);
}

// ---- per-user row offsets (interact_rows sorted) ----
__global__ void rowstart_kernel(const int* __restrict__ rows, int* __restrict__ rowstart) {
    int r = blockIdx.x * blockDim.x + threadIdx.x;
    if (r > N_USERS) return;
    int lo = 0, hi = N_INTERACT;
    while (lo < hi) {
        int mid = (lo + hi) >> 1;
        if (rows[mid] < r) lo = mid + 1; else hi = mid;
    }
    rowstart[r] = lo;
}

// ---- KG hop (fp32): gather + normalize + e_res(items) + SNORM; nrows param ----
__global__ void kg_hop(const int* __restrict__ rowptr, const int* __restrict__ tails,
                       const float* __restrict__ icnt, const float* __restrict__ Ain,
                       float* __restrict__ Aout, float* __restrict__ ER,
                       float* __restrict__ snorm, int nrows) {
    int wid = (blockIdx.x * blockDim.x + threadIdx.x) >> 6;
    int lane = threadIdx.x & 63;
    int g = lane >> 4, gl = lane & 15;
    if (wid >= nrows) return;
    int s = rowptr[wid], t = rowptr[wid + 1];
    float4 acc = {0.f, 0.f, 0.f, 0.f};
    int e = s + g;
    if (e < t) {
        int c = tails[e];
        float4 r = *(const float4*)(Ain + (size_t)c * D + gl * 4);
        int e2 = e + 4;
        int c2 = (e2 < t) ? tails[e2] : 0;
        while (true) {
            float4 r2 = {0.f, 0.f, 0.f, 0.f};
            if (e2 < t) r2 = *(const float4*)(Ain + (size_t)c2 * D + gl * 4);
            int e3 = e2 + 4;
            int c3 = (e3 < t) ? tails[e3] : 0;
            acc.x += r.x; acc.y += r.y; acc.z += r.z; acc.w += r.w;
            if (e2 >= t) break;
            e2 = e3; c2 = c3; r = r2;
        }
    }
    acc.x += __shfl_xor(acc.x, 16, 64); acc.x += __shfl_xor(acc.x, 32, 64);
    acc.y += __shfl_xor(acc.y, 16, 64); acc.y += __shfl_xor(acc.y, 32, 64);
    acc.z += __shfl_xor(acc.z, 16, 64); acc.z += __shfl_xor(acc.z, 32, 64);
    acc.w += __shfl_xor(acc.w, 16, 64); acc.w += __shfl_xor(acc.w, 32, 64);
    float ss = acc.x * acc.x + acc.y * acc.y + acc.z * acc.z + acc.w * acc.w;
    ss += __shfl_xor(ss, 1, 64); ss += __shfl_xor(ss, 2, 64);
    ss += __shfl_xor(ss, 4, 64); ss += __shfl_xor(ss, 8, 64);
    float nrm = fmaxf(sqrtf(ss), 1e-12f);
    float inv = 1.0f / nrm;
    if (g == 0) {
        size_t o = (size_t)wid * D + gl * 4;
        float4 ev = {acc.x * inv, acc.y * inv, acc.z * inv, acc.w * inv};
        *(float4*)(Aout + o) = ev;
        if (wid < N_ITEMS) {                 // e_res only consumed as [:N_ITEMS]
            float4 er = *(const float4*)(ER + o);
            er.x += ev.x; er.y += ev.y; er.z += ev.z; er.w += ev.w;
            *(float4*)(ER + o) = er;
            if (gl == 0) snorm[wid] = nrm * icnt[wid];
        }
    }
}

// ---- per-user pipeline: mean pass (caches rows in LDS) + softmax pass from LDS ----
__global__ void user_hop(const float* __restrict__ E, const float* __restrict__ snorm,
                         const int* __restrict__ rowstart, const int* __restrict__ cols,
                         const float* __restrict__ vals, float* __restrict__ UR) {
    __shared__ float4 rcache[4][4][CSLOTS][16];   // [wave][group][slot][gl] = 24 KB
    __shared__ float  scache[4][4][CSLOTS];
    int wid = (blockIdx.x * blockDim.x + threadIdx.x) >> 6;
    int lane = threadIdx.x & 63;
    int wv = threadIdx.x >> 6;
    int g = lane >> 4, gl = lane & 15;
    if (wid >= N_USERS) return;
    int s = rowstart[wid], t = rowstart[wid + 1];

    // pass A: user_mean (weighted); cache first CSLOTS rows/group in LDS
    float4 mean = {0.f, 0.f, 0.f, 0.f};
    {
        int k = 0;
        for (int e = s + g; e < t; e += 4, ++k) {
            int c = cols[e];
            float sn = snorm[c];
            float4 r = *(const float4*)(E + (size_t)c * D + gl * 4);
            if (k < CSLOTS) {
                rcache[wv][g][k][gl] = r;
                if (gl == 0) scache[wv][g][k] = sn;
            }
            float w = vals[e] * sn;
            mean.x += w * r.x; mean.y += w * r.y;
            mean.z += w * r.z; mean.w += w * r.w;
        }
    }
    mean.x += __shfl_xor(mean.x, 16, 64); mean.x += __shfl_xor(mean.x, 32, 64);
    mean.y += __shfl_xor(mean.y, 16, 64); mean.y += __shfl_xor(mean.y, 32, 64);
    mean.z += __shfl_xor(mean.z, 16, 64); mean.z += __shfl_xor(mean.z, 32, 64);
    mean.w += __shfl_xor(mean.w, 16, 64); mean.w += __shfl_xor(mean.w, 32, 64);

    // pass B: per-group online softmax; rows from LDS (tail slots reload global)
    float m = -INFINITY, denom = 0.f;
    float4 acc = {0.f, 0.f, 0.f, 0.f};
    {
        int k = 0;
        for (int e = s + g; e < t; e += 4, ++k) {
            float sn; float4 r;
            if (k < CSLOTS) {
                r = rcache[wv][g][k][gl];
                sn = scache[wv][g][k];
            } else {
                int c = cols[e];
                sn = snorm[c];
                r = *(const float4*)(E + (size_t)c * D + gl * 4);
            }
            float4 il = {sn * r.x, sn * r.y, sn * r.z, sn * r.w};
            float dx = il.x - mean.x + EPS_PD;
            float dy = il.y - mean.y + EPS_PD;
            float dz = il.z - mean.z + EPS_PD;
            float dw = il.w - mean.w + EPS_PD;
            float ssl = dx * dx + dy * dy + dz * dz + dw * dw;
            ssl += __shfl_xor(ssl, 1, 64); ssl += __shfl_xor(ssl, 2, 64);
            ssl += __shfl_xor(ssl, 4, 64); ssl += __shfl_xor(ssl, 8, 64);
            float sc = sqrtf(ssl) * INV_TEMP;
            float m_new = fmaxf(m, sc);
            float scale = __expf(m - m_new);
            float ex = __expf(sc - m_new);
            denom = denom * scale + ex;
            acc.x = acc.x * scale + ex * il.x;
            acc.y = acc.y * scale + ex * il.y;
            acc.z = acc.z * scale + ex * il.z;
            acc.w = acc.w * scale + ex * il.w;
            m = m_new;
        }
    }
    // merge 4 group states
    float mg = fmaxf(m, __shfl_xor(m, 16, 64));
    mg = fmaxf(mg, __shfl_xor(mg, 32, 64));
    float scl = __expf(fmaxf(m - mg, -88.0f));   // fmax eats NaN from (-inf)-(-inf)
    denom *= scl;
    acc.x *= scl; acc.y *= scl; acc.z *= scl; acc.w *= scl;
    denom += __shfl_xor(denom, 16, 64); denom += __shfl_xor(denom, 32, 64);
    acc.x += __shfl_xor(acc.x, 16, 64); acc.x += __shfl_xor(acc.x, 32, 64);
    acc.y += __shfl_xor(acc.y, 16, 64); acc.y += __shfl_xor(acc.y, 32, 64);
    acc.z += __shfl_xor(acc.z, 16, 64); acc.z += __shfl_xor(acc.z, 32, 64);
    acc.w += __shfl_xor(acc.w, 16, 64); acc.w += __shfl_xor(acc.w, 32, 64);
    float invd = denom > 0.f ? 1.0f / denom : 0.f;
    acc.x *= invd; acc.y *= invd; acc.z *= invd; acc.w *= invd;
    float ss = acc.x * acc.x + acc.y * acc.y + acc.z * acc.z + acc.w * acc.w;
    ss += __shfl_xor(ss, 1, 64); ss += __shfl_xor(ss, 2, 64);
    ss += __shfl_xor(ss, 4, 64); ss += __shfl_xor(ss, 8, 64);
    float inv = 1.0f / fmaxf(sqrtf(ss), 1e-12f);
    if (g == 0) {
        size_t o = (size_t)wid * D + gl * 4;
        float4 u = *(const float4*)(UR + o);
        u.x += acc.x * inv; u.y += acc.y * inv; u.z += acc.z * inv; u.w += acc.w * inv;
        *(float4*)(UR + o) = u;
    }
}

// ---- adj gather SpMM over fp16 rows; fp32 epilogues ----
// MODE 0: acc = adj@X; Y(fp16) = acc; out = xa(fp32 from UR|ER) + acc
// MODE 1: out = (out + adj@X) / 3
__device__ __forceinline__ const float* xrow32(const float* U, const float* I, int c) {
    return (c < N_USERS) ? (U + (size_t)c * D) : (I + (size_t)(c - N_USERS) * D);
}

template <int MODE>
__global__ void adj_spmm(const int* __restrict__ rowptr, const int2* __restrict__ pair,
                         const f16* __restrict__ X, const float* __restrict__ XAU,
                         const float* __restrict__ XAI, f16* __restrict__ Y,
                         float* __restrict__ out) {
    int wid = (blockIdx.x * blockDim.x + threadIdx.x) >> 6;
    int lane = threadIdx.x & 63;
    int g = lane >> 4, gl = lane & 15;
    if (wid >= N_UI) return;
    int s = rowptr[wid], t = rowptr[wid + 1];
    float4 acc = {0.f, 0.f, 0.f, 0.f};
    int e = s + g;
    if (e < t) {
        int2 p = pair[e];
        float4 r = ld_h4(X + (size_t)p.x * D + gl * 4);
        int e2 = e + 4;
        int2 p2 = (e2 < t) ? pair[e2] : make_int2(0, 0);
        while (true) {
            float4 r2 = {0.f, 0.f, 0.f, 0.f};
            if (e2 < t) r2 = ld_h4(X + (size_t)p2.x * D + gl * 4);
            int e3 = e2 + 4;
            int2 p3 = (e3 < t) ? pair[e3] : make_int2(0, 0);
            float v = __int_as_float(p.y);
            acc.x += v * r.x; acc.y += v * r.y; acc.z += v * r.z; acc.w += v * r.w;
            if (e2 >= t) break;
            e2 = e3; p = p2; p2 = p3; r = r2;
        }
    }
    acc.x += __shfl_xor(acc.x, 16, 64); acc.x += __shfl_xor(acc.x, 32, 64);
    acc.y += __shfl_xor(acc.y, 16, 64); acc.y += __shfl_xor(acc.y, 32, 64);
    acc.z += __shfl_xor(acc.z, 16, 64); acc.z += __shfl_xor(acc.z, 32, 64);
    acc.w += __shfl_xor(acc.w, 16, 64); acc.w += __shfl_xor(acc.w, 32, 64);
    if (g == 0) {
        size_t o = (size_t)wid * D + gl * 4;
        if (MODE == 0) {
            st_h4(Y + o, acc);
            const float4 xa = *(const float4*)(xrow32(XAU, XAI, wid) + gl * 4);
            float4 ov = {xa.x + acc.x, xa.y + acc.y, xa.z + acc.z, xa.w + acc.w};
            *(float4*)(out + o) = ov;
        } else {
            float4 ov = *(const float4*)(out + o);
            ov.x = (ov.x + acc.x) * (1.0f / 3.0f);
            ov.y = (ov.y + acc.y) * (1.0f / 3.0f);
            ov.z = (ov.z + acc.z) * (1.0f / 3.0f);
            ov.w = (ov.w + acc.w) * (1.0f / 3.0f);
            *(float4*)(out + o) = ov;
        }
    }
}

extern "C" void kernel_launch(void* const* d_in, const int* in_sizes, int n_in,
                              void* d_out, int out_size, void* d_ws, size_t ws_size,
                              hipStream_t stream) {
    const float* all_embed     = (const float*)d_in[0];
    const float* interact_vals = (const float*)d_in[1];
    const float* adj_vals      = (const float*)d_in[2];
    const int*   edge_index    = (const int*)d_in[3];
    // d_in[4] = edge_type (unused)
    const int*   interact_rows = (const int*)d_in[5];
    const int*   interact_cols = (const int*)d_in[6];
    const int*   adj_rows      = (const int*)d_in[7];
    const int*   adj_cols      = (const int*)d_in[8];
    float* out = (float*)d_out;

    const size_t entN = (size_t)N_ENTITIES * D;   // 5,120,000
    const size_t usrN = (size_t)N_USERS * D;      // 3,200,000
    const size_t itmN = (size_t)N_ITEMS * D;      // 1,920,000

    float* cur = (float*)d_ws;
    float* UR = cur; cur += usrN;                 // u_res fp32
    float* ER = cur; cur += itmN;                 // e_res items fp32
    float* A0 = cur; cur += entN;                 // entity fp32 ping / later adj CSR
    float* A1 = cur; cur += entN;                 // entity fp32 pong / later XH,X1H
    float* ICNT  = cur; cur += N_ENTITIES;
    float* SNORM = cur; cur += N_ITEMS + 16;
    int* KG_CNT    = (int*)cur;
    int* KG_ROWPTR = KG_CNT + N_ENTITIES;          // N_ENTITIES+1 (+pad)
    int* KG_POS    = KG_ROWPTR + N_ENTITIES + 2;
    int* KG_TAIL   = KG_POS + N_ENTITIES;          // N_KG_EDGES
    int* ROWSTART  = KG_TAIL + N_KG_EDGES;         // N_USERS+1

    // fp16 x / x1 overlaid on A1 (dead after hop-2 kg_hop reads it)
    f16* XH  = (f16*)A1;                           // N_UI*D halves = 2.56M floats
    f16* X1H = XH + (size_t)N_UI * D;              // same size
    // adj CSR overlaid on A0 (dead after hop-2 user_hop reads item rows)
    int*  ADJ_CNT    = (int*)A0;
    int*  ADJ_ROWPTR = ADJ_CNT + N_UI;
    int*  ADJ_POS    = ADJ_ROWPTR + N_UI + 2;
    int2* ADJ_PAIR   = (int2*)(ADJ_POS + N_UI);    // even word offset -> 8B aligned

    // ---- KG CSR build + init ----
    hipMemsetAsync(KG_CNT, 0, N_ENTITIES * sizeof(int), stream);
    hist_kernel<<<(N_KG_EDGES + 255) / 256, 256, 0, stream>>>(edge_index, KG_CNT, N_KG_EDGES);
    icnt_kernel<<<(N_ENTITIES + 255) / 256, 256, 0, stream>>>(KG_CNT, ICNT);
    scan_kernel<<<1, SCAN_T, 0, stream>>>(KG_CNT, KG_ROWPTR, KG_POS, N_ENTITIES);
    kg_fill<<<NPASS * ((N_KG_EDGES + 255) / 256), 256, 0, stream>>>(edge_index, KG_POS, KG_TAIL);
    rowstart_kernel<<<(N_USERS + 256) / 256, 256, 0, stream>>>(interact_rows, ROWSTART);

    hipMemcpyAsync(UR, all_embed, usrN * sizeof(float), hipMemcpyDeviceToDevice, stream);
    hipMemcpyAsync(ER, all_embed + usrN, itmN * sizeof(float), hipMemcpyDeviceToDevice, stream);
    hipMemcpyAsync(A0, all_embed + usrN, entN * sizeof(float), hipMemcpyDeviceToDevice, stream);

    // ---- KG hops (hop 2 computes item rows only) ----
    kg_hop<<<N_ENTITIES / 4, 256, 0, stream>>>(KG_ROWPTR, KG_TAIL, ICNT, A0, A1, ER,
                                               SNORM, N_ENTITIES);
    user_hop<<<N_USERS / 4, 256, 0, stream>>>(A1, SNORM, ROWSTART, interact_cols,
                                              interact_vals, UR);
    kg_hop<<<N_ITEMS / 4, 256, 0, stream>>>(KG_ROWPTR, KG_TAIL, ICNT, A1, A0, ER,
                                            SNORM, N_ITEMS);
    user_hop<<<N_USERS / 4, 256, 0, stream>>>(A0, SNORM, ROWSTART, interact_cols,
                                              interact_vals, UR);

    // ---- x -> fp16 (XH overlays A1; A1 dead after hop-2 kg_hop) ----
    cvt16_kernel<<<(int)(usrN / 4 + 255) / 256, 256, 0, stream>>>(UR, XH, (int)(usrN / 4));
    cvt16_kernel<<<(int)(itmN / 4 + 255) / 256, 256, 0, stream>>>(ER, XH + usrN,
                                                                  (int)(itmN / 4));

    // ---- adj CSR build into A0 (dead after hop-2 user_hop) ----
    hipMemsetAsync(ADJ_CNT, 0, N_UI * sizeof(int), stream);
    hist_kernel<<<(N_ADJ + 255) / 256, 256, 0, stream>>>(adj_rows, ADJ_CNT, N_ADJ);
    scan_kernel<<<1, SCAN_T, 0, stream>>>(ADJ_CNT, ADJ_ROWPTR, ADJ_POS, N_UI);
    adj_fill<<<NPASS * ((N_ADJ + 255) / 256), 256, 0, stream>>>(adj_rows, adj_cols, adj_vals,
                                                                ADJ_POS, ADJ_PAIR);

    // ---- LGCN: x1 = adj@x -> X1H(fp16), out = x + x1; out = (out + adj@x1)/3 ----
    adj_spmm<0><<<N_UI / 4, 256, 0, stream>>>(ADJ_ROWPTR, ADJ_PAIR, XH, UR, ER, X1H, out);
    adj_spmm<1><<<N_UI / 4, 256, 0, stream>>>(ADJ_ROWPTR, ADJ_PAIR, X1H, nullptr, nullptr,
                                              nullptr, out);
}

// Round 7
// 828.503 us; speedup vs baseline: 1.1331x; 1.1331x over previous
//
#include <hip/hip_runtime.h>
#include <math.h>

#define N_USERS 50000
#define N_ITEMS 30000
#define N_ENTITIES 80000
#define N_UI (N_USERS + N_ITEMS)
#define D 64
#define N_KG_EDGES 2000000
#define N_INTERACT 1000000
#define N_ADJ 2000000
#define INV_TEMP 5.0f
#define EPS_PD 1e-6f
#define SCAN_T 1024
#define NB 313          // buckets: key >> 8, 80000/256 -> 313
#define EPB 8192        // edges per binA block

typedef _Float16 f16;

__device__ __forceinline__ float4 ld_h4(const f16* p) {
    struct h4 { f16 x, y, z, w; };
    h4 h = *(const h4*)p;
    return make_float4((float)h.x, (float)h.y, (float)h.z, (float)h.w);
}

__device__ __forceinline__ void st_h4(f16* p, float4 v) {
    struct h4 { f16 x, y, z, w; };
    h4 h = {(f16)v.x, (f16)v.y, (f16)v.z, (f16)v.w};
    *(h4*)p = h;
}

// ---- int histogram over keys ----
__global__ void hist_kernel(const int* __restrict__ keys, int* __restrict__ cnt, int n) {
    int e = blockIdx.x * blockDim.x + threadIdx.x;
    if (e < n) atomicAdd(&cnt[keys[e]], 1);
}

// ---- icnt = 1/max(cnt,1) ----
__global__ void icnt_kernel(const int* __restrict__ cnt, float* __restrict__ icnt) {
    int i = blockIdx.x * blockDim.x + threadIdx.x;
    if (i < N_ENTITIES) icnt[i] = 1.0f / fmaxf((float)cnt[i], 1.0f);
}

// ---- fp32 -> fp16 bulk convert (4 elems/thread) ----
__global__ void cvt16_kernel(const float* __restrict__ in, f16* __restrict__ outp, int n4) {
    int i = blockIdx.x * blockDim.x + threadIdx.x;
    if (i < n4) st_h4(outp + (size_t)i * 4, *(const float4*)(in + (size_t)i * 4));
}

// ---- single-block scan: rowptr[0]=0, rowptr[i+1]=incl ----
__global__ void scan_kernel(const int* __restrict__ cnt, int* __restrict__ rowptr, int n) {
    __shared__ int wpart[16];
    __shared__ int carry_s;
    int lane = threadIdx.x & 63;
    int wv = threadIdx.x >> 6;
    if (threadIdx.x == 0) { carry_s = 0; rowptr[0] = 0; }
    __syncthreads();
    for (int base = 0; base < n; base += SCAN_T) {
        int i = base + threadIdx.x;
        int x = (i < n) ? cnt[i] : 0;
        #pragma unroll
        for (int o = 1; o < 64; o <<= 1) {
            int t = __shfl_up(x, o, 64);
            if (lane >= o) x += t;
        }
        if (lane == 63) wpart[wv] = x;
        __syncthreads();
        if (wv == 0) {
            int p = (lane < 16) ? wpart[lane] : 0;
            #pragma unroll
            for (int o = 1; o < 16; o <<= 1) {
                int t = __shfl_up(p, o, 64);
                if (lane >= o) p += t;
            }
            if (lane < 16) wpart[lane] = p;
        }
        __syncthreads();
        int add = carry_s + (wv > 0 ? wpart[wv - 1] : 0);
        int incl = x + add;
        if (i < n) rowptr[i + 1] = incl;
        __syncthreads();
        if (threadIdx.x == SCAN_T - 1) carry_s = incl;
        __syncthreads();
    }
}

// ---- bucket cursor init: bcur[b] = rowptr[min(b*256, nkeys)] ----
__global__ void bcur_init(const int* __restrict__ rowptr, int* __restrict__ bcur, int nkeys) {
    int b = blockIdx.x * blockDim.x + threadIdx.x;
    if (b < NB) bcur[b] = rowptr[min(b << 8, nkeys)];
}

// ---- binA (KG): block-local counting sort into bucket-contiguous runs ----
__global__ void binA_kg(const int* __restrict__ ei, int* __restrict__ bcur,
                        int2* __restrict__ binned, int n) {
    __shared__ int hist[NB + 7], base[NB + 7];
    for (int i = threadIdx.x; i < NB; i += 256) hist[i] = 0;
    __syncthreads();
    int e0 = blockIdx.x * EPB;
    for (int i = threadIdx.x; i < EPB; i += 256) {
        int e = e0 + i;
        if (e < n) atomicAdd(&hist[ei[e] >> 8], 1);
    }
    __syncthreads();
    for (int b = threadIdx.x; b < NB; b += 256)
        base[b] = hist[b] ? atomicAdd(&bcur[b], hist[b]) : 0;
    __syncthreads();
    for (int i = threadIdx.x; i < NB; i += 256) hist[i] = 0;
    __syncthreads();
    for (int i = threadIdx.x; i < EPB; i += 256) {
        int e = e0 + i;
        if (e >= n) continue;
        int h = ei[e];
        int b = h >> 8;
        int slot = base[b] + atomicAdd(&hist[b], 1);
        binned[slot] = make_int2(h, ei[n + e]);
    }
}

// ---- binC (KG): one block per bucket; LDS per-head cursors; L2-resident dest ----
__global__ void binC_kg(const int* __restrict__ rowptr, const int2* __restrict__ binned,
                        int* __restrict__ tails) {
    __shared__ int cursor[256];
    int b = blockIdx.x;
    int k0 = b << 8;
    int nk = min(256, N_ENTITIES - k0);
    if ((int)threadIdx.x < nk) cursor[threadIdx.x] = rowptr[k0 + threadIdx.x];
    __syncthreads();
    int s = rowptr[k0];
    int t = rowptr[min(k0 + 256, N_ENTITIES)];
    for (int i = s + threadIdx.x; i < t; i += 256) {
        int2 p = binned[i];
        int slot = atomicAdd(&cursor[p.x & 255], 1);
        tails[slot] = p.y;
    }
}

// ---- binA (adj): payload (row,col) + val, SoA ----
__global__ void binA_adj(const int* __restrict__ rows, const int* __restrict__ cols,
                         const float* __restrict__ vals, int* __restrict__ bcur,
                         int2* __restrict__ rc, float* __restrict__ bv, int n) {
    __shared__ int hist[NB + 7], base[NB + 7];
    for (int i = threadIdx.x; i < NB; i += 256) hist[i] = 0;
    __syncthreads();
    int e0 = blockIdx.x * EPB;
    for (int i = threadIdx.x; i < EPB; i += 256) {
        int e = e0 + i;
        if (e < n) atomicAdd(&hist[rows[e] >> 8], 1);
    }
    __syncthreads();
    for (int b = threadIdx.x; b < NB; b += 256)
        base[b] = hist[b] ? atomicAdd(&bcur[b], hist[b]) : 0;
    __syncthreads();
    for (int i = threadIdx.x; i < NB; i += 256) hist[i] = 0;
    __syncthreads();
    for (int i = threadIdx.x; i < EPB; i += 256) {
        int e = e0 + i;
        if (e >= n) continue;
        int r = rows[e];
        int b = r >> 8;
        int slot = base[b] + atomicAdd(&hist[b], 1);
        rc[slot] = make_int2(r, cols[e]);
        bv[slot] = vals[e];
    }
}

// ---- binC (adj): fused (col,val) pairs into CSR order ----
__global__ void binC_adj(const int* __restrict__ rowptr, const int2* __restrict__ rc,
                         const float* __restrict__ bv, int2* __restrict__ pair) {
    __shared__ int cursor[256];
    int b = blockIdx.x;
    int k0 = b << 8;
    int nk = min(256, N_UI - k0);
    if ((int)threadIdx.x < nk) cursor[threadIdx.x] = rowptr[k0 + threadIdx.x];
    __syncthreads();
    int s = rowptr[k0];
    int t = rowptr[min(k0 + 256, N_UI)];
    for (int i = s + threadIdx.x; i < t; i += 256) {
        int2 p = rc[i];
        float v = bv[i];
        int slot = atomicAdd(&cursor[p.x & 255], 1);
        pair[slot] = make_int2(p.y, __float_as_int(v));
    }
}

// ---- per-user row offsets (interact_rows sorted) ----
__global__ void rowstart_kernel(const int* __restrict__ rows, int* __restrict__ rowstart) {
    int r = blockIdx.x * blockDim.x + threadIdx.x;
    if (r > N_USERS) return;
    int lo = 0, hi = N_INTERACT;
    while (lo < hi) {
        int mid = (lo + hi) >> 1;
        if (rows[mid] < r) lo = mid + 1; else hi = mid;
    }
    rowstart[r] = lo;
}

// ---- KG hop (fp32): gather + normalize + e_res(items) + SNORM; nrows param ----
__global__ void kg_hop(const int* __restrict__ rowptr, const int* __restrict__ tails,
                       const float* __restrict__ icnt, const float* __restrict__ Ain,
                       float* __restrict__ Aout, float* __restrict__ ER,
                       float* __restrict__ snorm, int nrows) {
    int wid = (blockIdx.x * blockDim.x + threadIdx.x) >> 6;
    int lane = threadIdx.x & 63;
    int g = lane >> 4, gl = lane & 15;
    if (wid >= nrows) return;
    int s = rowptr[wid], t = rowptr[wid + 1];
    float4 acc = {0.f, 0.f, 0.f, 0.f};
    int e = s + g;
    if (e < t) {
        int c = tails[e];
        float4 r = *(const float4*)(Ain + (size_t)c * D + gl * 4);
        int e2 = e + 4;
        int c2 = (e2 < t) ? tails[e2] : 0;
        while (true) {
            float4 r2 = {0.f, 0.f, 0.f, 0.f};
            if (e2 < t) r2 = *(const float4*)(Ain + (size_t)c2 * D + gl * 4);
            int e3 = e2 + 4;
            int c3 = (e3 < t) ? tails[e3] : 0;
            acc.x += r.x; acc.y += r.y; acc.z += r.z; acc.w += r.w;
            if (e2 >= t) break;
            e2 = e3; c2 = c3; r = r2;
        }
    }
    acc.x += __shfl_xor(acc.x, 16, 64); acc.x += __shfl_xor(acc.x, 32, 64);
    acc.y += __shfl_xor(acc.y, 16, 64); acc.y += __shfl_xor(acc.y, 32, 64);
    acc.z += __shfl_xor(acc.z, 16, 64); acc.z += __shfl_xor(acc.z, 32, 64);
    acc.w += __shfl_xor(acc.w, 16, 64); acc.w += __shfl_xor(acc.w, 32, 64);
    float ss = acc.x * acc.x + acc.y * acc.y + acc.z * acc.z + acc.w * acc.w;
    ss += __shfl_xor(ss, 1, 64); ss += __shfl_xor(ss, 2, 64);
    ss += __shfl_xor(ss, 4, 64); ss += __shfl_xor(ss, 8, 64);
    float nrm = fmaxf(sqrtf(ss), 1e-12f);
    float inv = 1.0f / nrm;
    if (g == 0) {
        size_t o = (size_t)wid * D + gl * 4;
        float4 ev = {acc.x * inv, acc.y * inv, acc.z * inv, acc.w * inv};
        *(float4*)(Aout + o) = ev;
        if (wid < N_ITEMS) {                 // e_res only consumed as [:N_ITEMS]
            float4 er = *(const float4*)(ER + o);
            er.x += ev.x; er.y += ev.y; er.z += ev.z; er.w += ev.w;
            *(float4*)(ER + o) = er;
            if (gl == 0) snorm[wid] = nrm * icnt[wid];
        }
    }
}

// ---- per-user pipeline: mean pass + 4 independent online-softmax chains ----
__global__ void user_hop(const float* __restrict__ E, const float* __restrict__ snorm,
                         const int* __restrict__ rowstart, const int* __restrict__ cols,
                         const float* __restrict__ vals, float* __restrict__ UR) {
    int wid = (blockIdx.x * blockDim.x + threadIdx.x) >> 6;
    int lane = threadIdx.x & 63;
    int g = lane >> 4, gl = lane & 15;
    if (wid >= N_USERS) return;
    int s = rowstart[wid], t = rowstart[wid + 1];

    // pass A: user_mean (weighted), pipelined gather
    float4 mean = {0.f, 0.f, 0.f, 0.f};
    {
        int e = s + g;
        if (e < t) {
            int c = cols[e];
            float w = vals[e] * snorm[c];
            float4 r = *(const float4*)(E + (size_t)c * D + gl * 4);
            int e2 = e + 4;
            while (true) {
                float w2 = 0.f; float4 r2 = {0.f, 0.f, 0.f, 0.f};
                bool more = (e2 < t);
                if (more) {
                    int c2 = cols[e2];
                    w2 = vals[e2] * snorm[c2];
                    r2 = *(const float4*)(E + (size_t)c2 * D + gl * 4);
                }
                mean.x += w * r.x; mean.y += w * r.y;
                mean.z += w * r.z; mean.w += w * r.w;
                if (!more) break;
                w = w2; r = r2; e2 += 4;
            }
        }
    }
    mean.x += __shfl_xor(mean.x, 16, 64); mean.x += __shfl_xor(mean.x, 32, 64);
    mean.y += __shfl_xor(mean.y, 16, 64); mean.y += __shfl_xor(mean.y, 32, 64);
    mean.z += __shfl_xor(mean.z, 16, 64); mean.z += __shfl_xor(mean.z, 32, 64);
    mean.w += __shfl_xor(mean.w, 16, 64); mean.w += __shfl_xor(mean.w, 32, 64);

    // pass B: per-group online softmax, one-edge-ahead prefetch
    float m = -INFINITY, denom = 0.f;
    float4 acc = {0.f, 0.f, 0.f, 0.f};
    {
        int e = s + g;
        if (e < t) {
            int c = cols[e];
            float sn = snorm[c];
            float4 r = *(const float4*)(E + (size_t)c * D + gl * 4);
            int e2 = e + 4;
            while (true) {
                float sn2 = 0.f; float4 r2 = {0.f, 0.f, 0.f, 0.f};
                bool more = (e2 < t);
                if (more) {
                    int c2 = cols[e2];
                    sn2 = snorm[c2];
                    r2 = *(const float4*)(E + (size_t)c2 * D + gl * 4);
                }
                float4 il = {sn * r.x, sn * r.y, sn * r.z, sn * r.w};
                float dx = il.x - mean.x + EPS_PD;
                float dy = il.y - mean.y + EPS_PD;
                float dz = il.z - mean.z + EPS_PD;
                float dw = il.w - mean.w + EPS_PD;
                float ssl = dx * dx + dy * dy + dz * dz + dw * dw;
                ssl += __shfl_xor(ssl, 1, 64); ssl += __shfl_xor(ssl, 2, 64);
                ssl += __shfl_xor(ssl, 4, 64); ssl += __shfl_xor(ssl, 8, 64);
                float sc = sqrtf(ssl) * INV_TEMP;
                float m_new = fmaxf(m, sc);
                float scale = __expf(m - m_new);
                float ex = __expf(sc - m_new);
                denom = denom * scale + ex;
                acc.x = acc.x * scale + ex * il.x;
                acc.y = acc.y * scale + ex * il.y;
                acc.z = acc.z * scale + ex * il.z;
                acc.w = acc.w * scale + ex * il.w;
                m = m_new;
                if (!more) break;
                sn = sn2; r = r2; e2 += 4;
            }
        }
    }
    // merge 4 group states
    float mg = fmaxf(m, __shfl_xor(m, 16, 64));
    mg = fmaxf(mg, __shfl_xor(mg, 32, 64));
    float scl = __expf(fmaxf(m - mg, -88.0f));   // fmax eats NaN from (-inf)-(-inf)
    denom *= scl;
    acc.x *= scl; acc.y *= scl; acc.z *= scl; acc.w *= scl;
    denom += __shfl_xor(denom, 16, 64); denom += __shfl_xor(denom, 32, 64);
    acc.x += __shfl_xor(acc.x, 16, 64); acc.x += __shfl_xor(acc.x, 32, 64);
    acc.y += __shfl_xor(acc.y, 16, 64); acc.y += __shfl_xor(acc.y, 32, 64);
    acc.z += __shfl_xor(acc.z, 16, 64); acc.z += __shfl_xor(acc.z, 32, 64);
    acc.w += __shfl_xor(acc.w, 16, 64); acc.w += __shfl_xor(acc.w, 32, 64);
    float invd = denom > 0.f ? 1.0f / denom : 0.f;
    acc.x *= invd; acc.y *= invd; acc.z *= invd; acc.w *= invd;
    float ss = acc.x * acc.x + acc.y * acc.y + acc.z * acc.z + acc.w * acc.w;
    ss += __shfl_xor(ss, 1, 64); ss += __shfl_xor(ss, 2, 64);
    ss += __shfl_xor(ss, 4, 64); ss += __shfl_xor(ss, 8, 64);
    float inv = 1.0f / fmaxf(sqrtf(ss), 1e-12f);
    if (g == 0) {
        size_t o = (size_t)wid * D + gl * 4;
        float4 u = *(const float4*)(UR + o);
        u.x += acc.x * inv; u.y += acc.y * inv; u.z += acc.z * inv; u.w += acc.w * inv;
        *(float4*)(UR + o) = u;
    }
}

// ---- adj gather SpMM over fp16 rows; fp32 epilogues ----
__device__ __forceinline__ const float* xrow32(const float* U, const float* I, int c) {
    return (c < N_USERS) ? (U + (size_t)c * D) : (I + (size_t)(c - N_USERS) * D);
}

template <int MODE>
__global__ void adj_spmm(const int* __restrict__ rowptr, const int2* __restrict__ pair,
                         const f16* __restrict__ X, const float* __restrict__ XAU,
                         const float* __restrict__ XAI, f16* __restrict__ Y,
                         float* __restrict__ out) {
    int wid = (blockIdx.x * blockDim.x + threadIdx.x) >> 6;
    int lane = threadIdx.x & 63;
    int g = lane >> 4, gl = lane & 15;
    if (wid >= N_UI) return;
    int s = rowptr[wid], t = rowptr[wid + 1];
    float4 acc = {0.f, 0.f, 0.f, 0.f};
    int e = s + g;
    if (e < t) {
        int2 p = pair[e];
        float4 r = ld_h4(X + (size_t)p.x * D + gl * 4);
        int e2 = e + 4;
        int2 p2 = (e2 < t) ? pair[e2] : make_int2(0, 0);
        while (true) {
            float4 r2 = {0.f, 0.f, 0.f, 0.f};
            if (e2 < t) r2 = ld_h4(X + (size_t)p2.x * D + gl * 4);
            int e3 = e2 + 4;
            int2 p3 = (e3 < t) ? pair[e3] : make_int2(0, 0);
            float v = __int_as_float(p.y);
            acc.x += v * r.x; acc.y += v * r.y; acc.z += v * r.z; acc.w += v * r.w;
            if (e2 >= t) break;
            e2 = e3; p = p2; p2 = p3; r = r2;
        }
    }
    acc.x += __shfl_xor(acc.x, 16, 64); acc.x += __shfl_xor(acc.x, 32, 64);
    acc.y += __shfl_xor(acc.y, 16, 64); acc.y += __shfl_xor(acc.y, 32, 64);
    acc.z += __shfl_xor(acc.z, 16, 64); acc.z += __shfl_xor(acc.z, 32, 64);
    acc.w += __shfl_xor(acc.w, 16, 64); acc.w += __shfl_xor(acc.w, 32, 64);
    if (g == 0) {
        size_t o = (size_t)wid * D + gl * 4;
        if (MODE == 0) {
            st_h4(Y + o, acc);
            const float4 xa = *(const float4*)(xrow32(XAU, XAI, wid) + gl * 4);
            float4 ov = {xa.x + acc.x, xa.y + acc.y, xa.z + acc.z, xa.w + acc.w};
            *(float4*)(out + o) = ov;
        } else {
            float4 ov = *(const float4*)(out + o);
            ov.x = (ov.x + acc.x) * (1.0f / 3.0f);
            ov.y = (ov.y + acc.y) * (1.0f / 3.0f);
            ov.z = (ov.z + acc.z) * (1.0f / 3.0f);
            ov.w = (ov.w + acc.w) * (1.0f / 3.0f);
            *(float4*)(out + o) = ov;
        }
    }
}

extern "C" void kernel_launch(void* const* d_in, const int* in_sizes, int n_in,
                              void* d_out, int out_size, void* d_ws, size_t ws_size,
                              hipStream_t stream) {
    const float* all_embed     = (const float*)d_in[0];
    const float* interact_vals = (const float*)d_in[1];
    const float* adj_vals      = (const float*)d_in[2];
    const int*   edge_index    = (const int*)d_in[3];
    // d_in[4] = edge_type (unused)
    const int*   interact_rows = (const int*)d_in[5];
    const int*   interact_cols = (const int*)d_in[6];
    const int*   adj_rows      = (const int*)d_in[7];
    const int*   adj_cols      = (const int*)d_in[8];
    float* out = (float*)d_out;

    const size_t entN = (size_t)N_ENTITIES * D;   // 5,120,000
    const size_t usrN = (size_t)N_USERS * D;      // 3,200,000
    const size_t itmN = (size_t)N_ITEMS * D;      // 1,920,000

    float* cur = (float*)d_ws;
    float* UR = cur; cur += usrN;                 // u_res fp32
    float* ER = cur; cur += itmN;                 // e_res items fp32
    float* A0 = cur; cur += entN;                 // entity pong / later adj CSR(PAIR)
    float* A1 = cur; cur += entN;                 // kg-binned / entity ping / rc / XH,X1H
    int* KG_TAIL = (int*)cur; cur += N_KG_EDGES;  // tails; later bv overlay
    float* ICNT  = cur; cur += N_ENTITIES;
    float* SNORM = cur; cur += N_ITEMS + 16;
    int* KG_CNT    = (int*)cur;
    int* KG_ROWPTR = KG_CNT + N_ENTITIES;          // N_ENTITIES+2
    int* BCUR      = KG_ROWPTR + N_ENTITIES + 2;   // NB (+pad), reused for adj
    int* ROWSTART  = BCUR + NB + 7;                // N_USERS+1

    // overlays (timeline-disjoint)
    int2* KG_BIN = (int2*)A1;                      // 2M int2, dead before kg_hop1 writes A1
    int*  ADJ_CNT    = (int*)A0;                   // after hop2 user_hop, A0 dead
    int*  ADJ_ROWPTR = ADJ_CNT + N_UI;             // N_UI+2
    int2* ADJ_PAIR   = (int2*)(ADJ_ROWPTR + N_UI + 2);  // even word offset -> 8B aligned
    int2* ADJ_RC = (int2*)A1;                      // after hop2 kg_hop reads A1
    float* ADJ_V = (float*)KG_TAIL;                // TAIL dead after hop2 kg_hop
    f16* XH  = (f16*)A1;                           // after binC_adj, rc dead
    f16* X1H = XH + (size_t)N_UI * D;

    const int binA_grid = (N_KG_EDGES + EPB - 1) / EPB;   // 245 (same for adj)

    // ---- KG CSR build (hist -> scan -> bin -> fill) ----
    hipMemsetAsync(KG_CNT, 0, N_ENTITIES * sizeof(int), stream);
    hist_kernel<<<(N_KG_EDGES + 255) / 256, 256, 0, stream>>>(edge_index, KG_CNT, N_KG_EDGES);
    icnt_kernel<<<(N_ENTITIES + 255) / 256, 256, 0, stream>>>(KG_CNT, ICNT);
    scan_kernel<<<1, SCAN_T, 0, stream>>>(KG_CNT, KG_ROWPTR, N_ENTITIES);
    bcur_init<<<2, 256, 0, stream>>>(KG_ROWPTR, BCUR, N_ENTITIES);
    binA_kg<<<binA_grid, 256, 0, stream>>>(edge_index, BCUR, KG_BIN, N_KG_EDGES);
    binC_kg<<<NB, 256, 0, stream>>>(KG_ROWPTR, KG_BIN, KG_TAIL);
    rowstart_kernel<<<(N_USERS + 256) / 256, 256, 0, stream>>>(interact_rows, ROWSTART);

    hipMemcpyAsync(UR, all_embed, usrN * sizeof(float), hipMemcpyDeviceToDevice, stream);
    hipMemcpyAsync(ER, all_embed + usrN, itmN * sizeof(float), hipMemcpyDeviceToDevice, stream);

    // ---- KG hops (hop 1 reads all_embed directly; hop 2 items only) ----
    kg_hop<<<N_ENTITIES / 4, 256, 0, stream>>>(KG_ROWPTR, KG_TAIL, ICNT, all_embed + usrN,
                                               A1, ER, SNORM, N_ENTITIES);
    user_hop<<<N_USERS / 4, 256, 0, stream>>>(A1, SNORM, ROWSTART, interact_cols,
                                              interact_vals, UR);
    kg_hop<<<N_ITEMS / 4, 256, 0, stream>>>(KG_ROWPTR, KG_TAIL, ICNT, A1, A0, ER,
                                            SNORM, N_ITEMS);
    user_hop<<<N_USERS / 4, 256, 0, stream>>>(A0, SNORM, ROWSTART, interact_cols,
                                              interact_vals, UR);

    // ---- adj CSR build (A0, A1, TAIL now dead) ----
    hipMemsetAsync(ADJ_CNT, 0, N_UI * sizeof(int), stream);
    hist_kernel<<<(N_ADJ + 255) / 256, 256, 0, stream>>>(adj_rows, ADJ_CNT, N_ADJ);
    scan_kernel<<<1, SCAN_T, 0, stream>>>(ADJ_CNT, ADJ_ROWPTR, N_UI);
    bcur_init<<<2, 256, 0, stream>>>(ADJ_ROWPTR, BCUR, N_UI);
    binA_adj<<<binA_grid, 256, 0, stream>>>(adj_rows, adj_cols, adj_vals, BCUR,
                                            ADJ_RC, ADJ_V, N_ADJ);
    binC_adj<<<NB, 256, 0, stream>>>(ADJ_ROWPTR, ADJ_RC, ADJ_V, ADJ_PAIR);

    // ---- x -> fp16 (XH overlays A1; rc dead after binC_adj) ----
    cvt16_kernel<<<(int)(usrN / 4 + 255) / 256, 256, 0, stream>>>(UR, XH, (int)(usrN / 4));
    cvt16_kernel<<<(int)(itmN / 4 + 255) / 256, 256, 0, stream>>>(ER, XH + usrN,
                                                                  (int)(itmN / 4));

    // ---- LGCN: x1 = adj@x -> X1H(fp16), out = x + x1; out = (out + adj@x1)/3 ----
    adj_spmm<0><<<N_UI / 4, 256, 0, stream>>>(ADJ_ROWPTR, ADJ_PAIR, XH, UR, ER, X1H, out);
    adj_spmm<1><<<N_UI / 4, 256, 0, stream>>>(ADJ_ROWPTR, ADJ_PAIR, X1H, nullptr, nullptr,
                                              nullptr, out);
}

// Round 8
// 574.118 us; speedup vs baseline: 1.6351x; 1.4431x over previous
//
#include <hip/hip_runtime.h>
#include <math.h>

#define N_USERS 50000
#define N_ITEMS 30000
#define N_ENTITIES 80000
#define N_UI (N_USERS + N_ITEMS)
#define D 64
#define N_KG_EDGES 2000000
#define N_INTERACT 1000000
#define N_ADJ 2000000
#define INV_TEMP 5.0f
#define EPS_PD 1e-6f
#define SHIFT 7         // bucket = key >> 7
#define NB 625          // 80000 / 128
#define BKEYS 128
#define BMASK 127
#define EPB 8192        // edges per binA/bhist block

typedef _Float16 f16;

__device__ __forceinline__ float4 ld_h4(const f16* p) {
    struct h4 { f16 x, y, z, w; };
    h4 h = *(const h4*)p;
    return make_float4((float)h.x, (float)h.y, (float)h.z, (float)h.w);
}

__device__ __forceinline__ void st_h4(f16* p, float4 v) {
    struct h4 { f16 x, y, z, w; };
    h4 h = {(f16)v.x, (f16)v.y, (f16)v.z, (f16)v.w};
    *(h4*)p = h;
}

// ---- fp32 -> fp16 bulk convert (4 elems/thread) ----
__global__ void cvt16_kernel(const float* __restrict__ in, f16* __restrict__ outp, int n4) {
    int i = blockIdx.x * blockDim.x + threadIdx.x;
    if (i < n4) st_h4(outp + (size_t)i * 4, *(const float4*)(in + (size_t)i * 4));
}

// ---- bucket histogram, LDS-privatized: ~NB global atomics per block ----
__global__ void bhist_kernel(const int* __restrict__ keys, int* __restrict__ bcnt, int n) {
    __shared__ int h[NB];
    for (int i = threadIdx.x; i < NB; i += 256) h[i] = 0;
    __syncthreads();
    int e0 = blockIdx.x * EPB;
    int e1 = min(e0 + EPB, n);
    for (int e = e0 + (int)threadIdx.x; e < e1; e += 256)
        atomicAdd(&h[keys[e] >> SHIFT], 1);
    __syncthreads();
    for (int i = threadIdx.x; i < NB; i += 256)
        if (h[i]) atomicAdd(&bcnt[i], h[i]);
}

// ---- single-block scan over NB buckets: boff[0]=0, boff[i+1]=incl, bcur[i]=excl ----
__global__ void bscan_kernel(const int* __restrict__ cnt, int* __restrict__ boff,
                             int* __restrict__ bcur, int n) {
    __shared__ int wp[4];
    __shared__ int carry_s;
    int lane = threadIdx.x & 63, wv = threadIdx.x >> 6;
    if (threadIdx.x == 0) { carry_s = 0; boff[0] = 0; }
    __syncthreads();
    for (int base = 0; base < n; base += 256) {
        int i = base + (int)threadIdx.x;
        int v = (i < n) ? cnt[i] : 0;
        int x = v;
        #pragma unroll
        for (int o = 1; o < 64; o <<= 1) {
            int t = __shfl_up(x, o, 64);
            if (lane >= o) x += t;
        }
        if (lane == 63) wp[wv] = x;
        __syncthreads();
        int add = carry_s;
        for (int j = 0; j < wv; ++j) add += wp[j];
        int incl = x + add;
        if (i < n) { boff[i + 1] = incl; bcur[i] = incl - v; }
        __syncthreads();
        if (threadIdx.x == 255) carry_s = incl;
        __syncthreads();
    }
}

// ---- binA (KG): block-local counting sort into bucket-contiguous runs ----
__global__ void binA_kg(const int* __restrict__ ei, int* __restrict__ bcur,
                        int2* __restrict__ binned, int n) {
    __shared__ int hist[NB], base[NB];
    for (int i = threadIdx.x; i < NB; i += 256) hist[i] = 0;
    __syncthreads();
    int e0 = blockIdx.x * EPB;
    for (int i = threadIdx.x; i < EPB; i += 256) {
        int e = e0 + i;
        if (e < n) atomicAdd(&hist[ei[e] >> SHIFT], 1);
    }
    __syncthreads();
    for (int b = threadIdx.x; b < NB; b += 256)
        base[b] = hist[b] ? atomicAdd(&bcur[b], hist[b]) : 0;
    __syncthreads();
    for (int i = threadIdx.x; i < NB; i += 256) hist[i] = 0;
    __syncthreads();
    for (int i = threadIdx.x; i < EPB; i += 256) {
        int e = e0 + i;
        if (e >= n) continue;
        int h = ei[e];
        int b = h >> SHIFT;
        int slot = base[b] + atomicAdd(&hist[b], 1);
        binned[slot] = make_int2(h, ei[n + e]);
    }
}

// ---- binC (KG): per-bucket key-count + LDS scan -> rowptr, icnt, scatter tails ----
__global__ void binC_kg(const int* __restrict__ boff, const int2* __restrict__ binned,
                        int* __restrict__ tails, int* __restrict__ rowptr,
                        float* __restrict__ icnt) {
    __shared__ int cnt_s[BKEYS];
    __shared__ int cur_s[BKEYS];
    __shared__ int wp2[2];
    int b = blockIdx.x;
    int k0 = b << SHIFT;
    int s = boff[b], t = boff[b + 1];
    if (threadIdx.x < BKEYS) cnt_s[threadIdx.x] = 0;
    __syncthreads();
    for (int i = s + (int)threadIdx.x; i < t; i += 256)
        atomicAdd(&cnt_s[binned[i].x & BMASK], 1);
    __syncthreads();
    int lane = threadIdx.x & 63, wv = threadIdx.x >> 6;
    int v = (threadIdx.x < BKEYS) ? cnt_s[threadIdx.x] : 0;
    int x = v;
    #pragma unroll
    for (int o = 1; o < 64; o <<= 1) {
        int tt = __shfl_up(x, o, 64);
        if (lane >= o) x += tt;
    }
    if (threadIdx.x < BKEYS && lane == 63) wp2[wv] = x;
    __syncthreads();
    int add = (wv == 1) ? wp2[0] : 0;
    int excl = s + (x - v) + add;
    if (threadIdx.x < BKEYS) {
        cur_s[threadIdx.x] = excl;
        rowptr[k0 + threadIdx.x] = excl;
        icnt[k0 + threadIdx.x] = 1.0f / fmaxf((float)v, 1.0f);
    }
    if (b == (int)gridDim.x - 1 && threadIdx.x == 0) rowptr[N_ENTITIES] = t;
    __syncthreads();
    for (int i = s + (int)threadIdx.x; i < t; i += 256) {
        int2 p = binned[i];
        int slot = atomicAdd(&cur_s[p.x & BMASK], 1);
        tails[slot] = p.y;
    }
}

// ---- binA (adj): payload (row,col) + val, SoA ----
__global__ void binA_adj(const int* __restrict__ rows, const int* __restrict__ cols,
                         const float* __restrict__ vals, int* __restrict__ bcur,
                         int2* __restrict__ rc, float* __restrict__ bv, int n) {
    __shared__ int hist[NB], base[NB];
    for (int i = threadIdx.x; i < NB; i += 256) hist[i] = 0;
    __syncthreads();
    int e0 = blockIdx.x * EPB;
    for (int i = threadIdx.x; i < EPB; i += 256) {
        int e = e0 + i;
        if (e < n) atomicAdd(&hist[rows[e] >> SHIFT], 1);
    }
    __syncthreads();
    for (int b = threadIdx.x; b < NB; b += 256)
        base[b] = hist[b] ? atomicAdd(&bcur[b], hist[b]) : 0;
    __syncthreads();
    for (int i = threadIdx.x; i < NB; i += 256) hist[i] = 0;
    __syncthreads();
    for (int i = threadIdx.x; i < EPB; i += 256) {
        int e = e0 + i;
        if (e >= n) continue;
        int r = rows[e];
        int b = r >> SHIFT;
        int slot = base[b] + atomicAdd(&hist[b], 1);
        rc[slot] = make_int2(r, cols[e]);
        bv[slot] = vals[e];
    }
}

// ---- binC (adj): per-bucket CSR rowptr + fused (col,val) scatter ----
__global__ void binC_adj(const int* __restrict__ boff, const int2* __restrict__ rc,
                         const float* __restrict__ bv, int2* __restrict__ pair,
                         int* __restrict__ rowptr) {
    __shared__ int cnt_s[BKEYS];
    __shared__ int cur_s[BKEYS];
    __shared__ int wp2[2];
    int b = blockIdx.x;
    int k0 = b << SHIFT;
    int s = boff[b], t = boff[b + 1];
    if (threadIdx.x < BKEYS) cnt_s[threadIdx.x] = 0;
    __syncthreads();
    for (int i = s + (int)threadIdx.x; i < t; i += 256)
        atomicAdd(&cnt_s[rc[i].x & BMASK], 1);
    __syncthreads();
    int lane = threadIdx.x & 63, wv = threadIdx.x >> 6;
    int v = (threadIdx.x < BKEYS) ? cnt_s[threadIdx.x] : 0;
    int x = v;
    #pragma unroll
    for (int o = 1; o < 64; o <<= 1) {
        int tt = __shfl_up(x, o, 64);
        if (lane >= o) x += tt;
    }
    if (threadIdx.x < BKEYS && lane == 63) wp2[wv] = x;
    __syncthreads();
    int add = (wv == 1) ? wp2[0] : 0;
    int excl = s + (x - v) + add;
    if (threadIdx.x < BKEYS) {
        cur_s[threadIdx.x] = excl;
        rowptr[k0 + threadIdx.x] = excl;
    }
    if (b == (int)gridDim.x - 1 && threadIdx.x == 0) rowptr[N_UI] = t;
    __syncthreads();
    for (int i = s + (int)threadIdx.x; i < t; i += 256) {
        int2 p = rc[i];
        float vv = bv[i];
        int slot = atomicAdd(&cur_s[p.x & BMASK], 1);
        pair[slot] = make_int2(p.y, __float_as_int(vv));
    }
}

// ---- per-user row offsets (interact_rows sorted) ----
__global__ void rowstart_kernel(const int* __restrict__ rows, int* __restrict__ rowstart) {
    int r = blockIdx.x * blockDim.x + threadIdx.x;
    if (r > N_USERS) return;
    int lo = 0, hi = N_INTERACT;
    while (lo < hi) {
        int mid = (lo + hi) >> 1;
        if (rows[mid] < r) lo = mid + 1; else hi = mid;
    }
    rowstart[r] = lo;
}

// ---- KG hop (fp32): gather + normalize + e_res(items) + SNORM; nrows param ----
__global__ void kg_hop(const int* __restrict__ rowptr, const int* __restrict__ tails,
                       const float* __restrict__ icnt, const float* __restrict__ Ain,
                       float* __restrict__ Aout, float* __restrict__ ER,
                       float* __restrict__ snorm, int nrows) {
    int wid = (blockIdx.x * blockDim.x + threadIdx.x) >> 6;
    int lane = threadIdx.x & 63;
    int g = lane >> 4, gl = lane & 15;
    if (wid >= nrows) return;
    int s = rowptr[wid], t = rowptr[wid + 1];
    float4 acc = {0.f, 0.f, 0.f, 0.f};
    int e = s + g;
    if (e < t) {
        int c = tails[e];
        float4 r = *(const float4*)(Ain + (size_t)c * D + gl * 4);
        int e2 = e + 4;
        int c2 = (e2 < t) ? tails[e2] : 0;
        while (true) {
            float4 r2 = {0.f, 0.f, 0.f, 0.f};
            if (e2 < t) r2 = *(const float4*)(Ain + (size_t)c2 * D + gl * 4);
            int e3 = e2 + 4;
            int c3 = (e3 < t) ? tails[e3] : 0;
            acc.x += r.x; acc.y += r.y; acc.z += r.z; acc.w += r.w;
            if (e2 >= t) break;
            e2 = e3; c2 = c3; r = r2;
        }
    }
    acc.x += __shfl_xor(acc.x, 16, 64); acc.x += __shfl_xor(acc.x, 32, 64);
    acc.y += __shfl_xor(acc.y, 16, 64); acc.y += __shfl_xor(acc.y, 32, 64);
    acc.z += __shfl_xor(acc.z, 16, 64); acc.z += __shfl_xor(acc.z, 32, 64);
    acc.w += __shfl_xor(acc.w, 16, 64); acc.w += __shfl_xor(acc.w, 32, 64);
    float ss = acc.x * acc.x + acc.y * acc.y + acc.z * acc.z + acc.w * acc.w;
    ss += __shfl_xor(ss, 1, 64); ss += __shfl_xor(ss, 2, 64);
    ss += __shfl_xor(ss, 4, 64); ss += __shfl_xor(ss, 8, 64);
    float nrm = fmaxf(sqrtf(ss), 1e-12f);
    float inv = 1.0f / nrm;
    if (g == 0) {
        size_t o = (size_t)wid * D + gl * 4;
        float4 ev = {acc.x * inv, acc.y * inv, acc.z * inv, acc.w * inv};
        *(float4*)(Aout + o) = ev;
        if (wid < N_ITEMS) {                 // e_res only consumed as [:N_ITEMS]
            float4 er = *(const float4*)(ER + o);
            er.x += ev.x; er.y += ev.y; er.z += ev.z; er.w += ev.w;
            *(float4*)(ER + o) = er;
            if (gl == 0) snorm[wid] = nrm * icnt[wid];
        }
    }
}

// ---- per-user pipeline: mean pass + 4 independent online-softmax chains ----
__global__ void user_hop(const float* __restrict__ E, const float* __restrict__ snorm,
                         const int* __restrict__ rowstart, const int* __restrict__ cols,
                         const float* __restrict__ vals, float* __restrict__ UR) {
    int wid = (blockIdx.x * blockDim.x + threadIdx.x) >> 6;
    int lane = threadIdx.x & 63;
    int g = lane >> 4, gl = lane & 15;
    if (wid >= N_USERS) return;
    int s = rowstart[wid], t = rowstart[wid + 1];

    // pass A: user_mean (weighted), pipelined gather
    float4 mean = {0.f, 0.f, 0.f, 0.f};
    {
        int e = s + g;
        if (e < t) {
            int c = cols[e];
            float w = vals[e] * snorm[c];
            float4 r = *(const float4*)(E + (size_t)c * D + gl * 4);
            int e2 = e + 4;
            while (true) {
                float w2 = 0.f; float4 r2 = {0.f, 0.f, 0.f, 0.f};
                bool more = (e2 < t);
                if (more) {
                    int c2 = cols[e2];
                    w2 = vals[e2] * snorm[c2];
                    r2 = *(const float4*)(E + (size_t)c2 * D + gl * 4);
                }
                mean.x += w * r.x; mean.y += w * r.y;
                mean.z += w * r.z; mean.w += w * r.w;
                if (!more) break;
                w = w2; r = r2; e2 += 4;
            }
        }
    }
    mean.x += __shfl_xor(mean.x, 16, 64); mean.x += __shfl_xor(mean.x, 32, 64);
    mean.y += __shfl_xor(mean.y, 16, 64); mean.y += __shfl_xor(mean.y, 32, 64);
    mean.z += __shfl_xor(mean.z, 16, 64); mean.z += __shfl_xor(mean.z, 32, 64);
    mean.w += __shfl_xor(mean.w, 16, 64); mean.w += __shfl_xor(mean.w, 32, 64);

    // pass B: per-group online softmax, one-edge-ahead prefetch
    float m = -INFINITY, denom = 0.f;
    float4 acc = {0.f, 0.f, 0.f, 0.f};
    {
        int e = s + g;
        if (e < t) {
            int c = cols[e];
            float sn = snorm[c];
            float4 r = *(const float4*)(E + (size_t)c * D + gl * 4);
            int e2 = e + 4;
            while (true) {
                float sn2 = 0.f; float4 r2 = {0.f, 0.f, 0.f, 0.f};
                bool more = (e2 < t);
                if (more) {
                    int c2 = cols[e2];
                    sn2 = snorm[c2];
                    r2 = *(const float4*)(E + (size_t)c2 * D + gl * 4);
                }
                float4 il = {sn * r.x, sn * r.y, sn * r.z, sn * r.w};
                float dx = il.x - mean.x + EPS_PD;
                float dy = il.y - mean.y + EPS_PD;
                float dz = il.z - mean.z + EPS_PD;
                float dw = il.w - mean.w + EPS_PD;
                float ssl = dx * dx + dy * dy + dz * dz + dw * dw;
                ssl += __shfl_xor(ssl, 1, 64); ssl += __shfl_xor(ssl, 2, 64);
                ssl += __shfl_xor(ssl, 4, 64); ssl += __shfl_xor(ssl, 8, 64);
                float sc = sqrtf(ssl) * INV_TEMP;
                float m_new = fmaxf(m, sc);
                float scale = __expf(m - m_new);
                float ex = __expf(sc - m_new);
                denom = denom * scale + ex;
                acc.x = acc.x * scale + ex * il.x;
                acc.y = acc.y * scale + ex * il.y;
                acc.z = acc.z * scale + ex * il.z;
                acc.w = acc.w * scale + ex * il.w;
                m = m_new;
                if (!more) break;
                sn = sn2; r = r2; e2 += 4;
            }
        }
    }
    // merge 4 group states
    float mg = fmaxf(m, __shfl_xor(m, 16, 64));
    mg = fmaxf(mg, __shfl_xor(mg, 32, 64));
    float scl = __expf(fmaxf(m - mg, -88.0f));   // fmax eats NaN from (-inf)-(-inf)
    denom *= scl;
    acc.x *= scl; acc.y *= scl; acc.z *= scl; acc.w *= scl;
    denom += __shfl_xor(denom, 16, 64); denom += __shfl_xor(denom, 32, 64);
    acc.x += __shfl_xor(acc.x, 16, 64); acc.x += __shfl_xor(acc.x, 32, 64);
    acc.y += __shfl_xor(acc.y, 16, 64); acc.y += __shfl_xor(acc.y, 32, 64);
    acc.z += __shfl_xor(acc.z, 16, 64); acc.z += __shfl_xor(acc.z, 32, 64);
    acc.w += __shfl_xor(acc.w, 16, 64); acc.w += __shfl_xor(acc.w, 32, 64);
    float invd = denom > 0.f ? 1.0f / denom : 0.f;
    acc.x *= invd; acc.y *= invd; acc.z *= invd; acc.w *= invd;
    float ss = acc.x * acc.x + acc.y * acc.y + acc.z * acc.z + acc.w * acc.w;
    ss += __shfl_xor(ss, 1, 64); ss += __shfl_xor(ss, 2, 64);
    ss += __shfl_xor(ss, 4, 64); ss += __shfl_xor(ss, 8, 64);
    float inv = 1.0f / fmaxf(sqrtf(ss), 1e-12f);
    if (g == 0) {
        size_t o = (size_t)wid * D + gl * 4;
        float4 u = *(const float4*)(UR + o);
        u.x += acc.x * inv; u.y += acc.y * inv; u.z += acc.z * inv; u.w += acc.w * inv;
        *(float4*)(UR + o) = u;
    }
}

// ---- adj gather SpMM over fp16 rows; fp32 epilogues ----
__device__ __forceinline__ const float* xrow32(const float* U, const float* I, int c) {
    return (c < N_USERS) ? (U + (size_t)c * D) : (I + (size_t)(c - N_USERS) * D);
}

template <int MODE>
__global__ void adj_spmm(const int* __restrict__ rowptr, const int2* __restrict__ pair,
                         const f16* __restrict__ X, const float* __restrict__ XAU,
                         const float* __restrict__ XAI, f16* __restrict__ Y,
                         float* __restrict__ out) {
    int wid = (blockIdx.x * blockDim.x + threadIdx.x) >> 6;
    int lane = threadIdx.x & 63;
    int g = lane >> 4, gl = lane & 15;
    if (wid >= N_UI) return;
    int s = rowptr[wid], t = rowptr[wid + 1];
    float4 acc = {0.f, 0.f, 0.f, 0.f};
    int e = s + g;
    if (e < t) {
        int2 p = pair[e];
        float4 r = ld_h4(X + (size_t)p.x * D + gl * 4);
        int e2 = e + 4;
        int2 p2 = (e2 < t) ? pair[e2] : make_int2(0, 0);
        while (true) {
            float4 r2 = {0.f, 0.f, 0.f, 0.f};
            if (e2 < t) r2 = ld_h4(X + (size_t)p2.x * D + gl * 4);
            int e3 = e2 + 4;
            int2 p3 = (e3 < t) ? pair[e3] : make_int2(0, 0);
            float v = __int_as_float(p.y);
            acc.x += v * r.x; acc.y += v * r.y; acc.z += v * r.z; acc.w += v * r.w;
            if (e2 >= t) break;
            e2 = e3; p = p2; p2 = p3; r = r2;
        }
    }
    acc.x += __shfl_xor(acc.x, 16, 64); acc.x += __shfl_xor(acc.x, 32, 64);
    acc.y += __shfl_xor(acc.y, 16, 64); acc.y += __shfl_xor(acc.y, 32, 64);
    acc.z += __shfl_xor(acc.z, 16, 64); acc.z += __shfl_xor(acc.z, 32, 64);
    acc.w += __shfl_xor(acc.w, 16, 64); acc.w += __shfl_xor(acc.w, 32, 64);
    if (g == 0) {
        size_t o = (size_t)wid * D + gl * 4;
        if (MODE == 0) {
            st_h4(Y + o, acc);
            const float4 xa = *(const float4*)(xrow32(XAU, XAI, wid) + gl * 4);
            float4 ov = {xa.x + acc.x, xa.y + acc.y, xa.z + acc.z, xa.w + acc.w};
            *(float4*)(out + o) = ov;
        } else {
            float4 ov = *(const float4*)(out + o);
            ov.x = (ov.x + acc.x) * (1.0f / 3.0f);
            ov.y = (ov.y + acc.y) * (1.0f / 3.0f);
            ov.z = (ov.z + acc.z) * (1.0f / 3.0f);
            ov.w = (ov.w + acc.w) * (1.0f / 3.0f);
            *(float4*)(out + o) = ov;
        }
    }
}

extern "C" void kernel_launch(void* const* d_in, const int* in_sizes, int n_in,
                              void* d_out, int out_size, void* d_ws, size_t ws_size,
                              hipStream_t stream) {
    const float* all_embed     = (const float*)d_in[0];
    const float* interact_vals = (const float*)d_in[1];
    const float* adj_vals      = (const float*)d_in[2];
    const int*   edge_index    = (const int*)d_in[3];
    // d_in[4] = edge_type (unused)
    const int*   interact_rows = (const int*)d_in[5];
    const int*   interact_cols = (const int*)d_in[6];
    const int*   adj_rows      = (const int*)d_in[7];
    const int*   adj_cols      = (const int*)d_in[8];
    float* out = (float*)d_out;

    const size_t entN = (size_t)N_ENTITIES * D;   // 5,120,000
    const size_t usrN = (size_t)N_USERS * D;      // 3,200,000
    const size_t itmN = (size_t)N_ITEMS * D;      // 1,920,000

    float* cur = (float*)d_ws;
    float* UR = cur; cur += usrN;                 // u_res fp32
    float* ER = cur; cur += itmN;                 // e_res items fp32
    float* A0 = cur; cur += entN;                 // entity pong / later adj CSR
    float* A1 = cur; cur += entN;                 // kg-binned / entity ping / rc / XH,X1H
    int* KG_TAIL = (int*)cur; cur += N_KG_EDGES;  // tails; later bv overlay
    float* ICNT  = cur; cur += N_ENTITIES;
    float* SNORM = cur; cur += N_ITEMS + 16;
    int* KG_ROWPTR = (int*)cur;                    // N_ENTITIES+1 (+pad)
    int* BCNT      = KG_ROWPTR + N_ENTITIES + 2;   // NB
    int* BOFF      = BCNT + NB + 1;                // NB+1
    int* BCUR      = BOFF + NB + 2;                // NB
    int* ROWSTART  = BCUR + NB + 1;                // N_USERS+1

    // overlays (timeline-disjoint)
    int2* KG_BIN = (int2*)A1;                      // dead before kg_hop1 writes A1
    int*  ADJ_ROWPTR = (int*)A0;                   // A0 dead after hop-2 user_hop
    int2* ADJ_PAIR   = (int2*)(ADJ_ROWPTR + N_UI + 2);  // even offset -> 8B aligned
    int2* ADJ_RC = (int2*)A1;                      // A1 dead after hop-2 kg_hop
    float* ADJ_V = (float*)KG_TAIL;                // TAIL dead after hop-2 kg_hop
    f16* XH  = (f16*)A1;                           // after binC_adj, rc dead
    f16* X1H = XH + (size_t)N_UI * D;

    const int binA_grid = (N_KG_EDGES + EPB - 1) / EPB;   // 245 (same for adj)

    // ---- KG CSR build: bucket-hist -> bucket-scan -> binA -> binC(rowptr+icnt) ----
    hipMemsetAsync(BCNT, 0, NB * sizeof(int), stream);
    bhist_kernel<<<binA_grid, 256, 0, stream>>>(edge_index, BCNT, N_KG_EDGES);
    bscan_kernel<<<1, 256, 0, stream>>>(BCNT, BOFF, BCUR, NB);
    binA_kg<<<binA_grid, 256, 0, stream>>>(edge_index, BCUR, KG_BIN, N_KG_EDGES);
    binC_kg<<<NB, 256, 0, stream>>>(BOFF, KG_BIN, KG_TAIL, KG_ROWPTR, ICNT);
    rowstart_kernel<<<(N_USERS + 256) / 256, 256, 0, stream>>>(interact_rows, ROWSTART);

    hipMemcpyAsync(UR, all_embed, usrN * sizeof(float), hipMemcpyDeviceToDevice, stream);
    hipMemcpyAsync(ER, all_embed + usrN, itmN * sizeof(float), hipMemcpyDeviceToDevice, stream);

    // ---- KG hops (hop 1 reads all_embed directly; hop 2 items only) ----
    kg_hop<<<N_ENTITIES / 4, 256, 0, stream>>>(KG_ROWPTR, KG_TAIL, ICNT, all_embed + usrN,
                                               A1, ER, SNORM, N_ENTITIES);
    user_hop<<<N_USERS / 4, 256, 0, stream>>>(A1, SNORM, ROWSTART, interact_cols,
                                              interact_vals, UR);
    kg_hop<<<N_ITEMS / 4, 256, 0, stream>>>(KG_ROWPTR, KG_TAIL, ICNT, A1, A0, ER,
                                            SNORM, N_ITEMS);
    user_hop<<<N_USERS / 4, 256, 0, stream>>>(A0, SNORM, ROWSTART, interact_cols,
                                              interact_vals, UR);

    // ---- adj CSR build (A0, A1, TAIL now dead) ----
    hipMemsetAsync(BCNT, 0, NB * sizeof(int), stream);
    bhist_kernel<<<binA_grid, 256, 0, stream>>>(adj_rows, BCNT, N_ADJ);
    bscan_kernel<<<1, 256, 0, stream>>>(BCNT, BOFF, BCUR, NB);
    binA_adj<<<binA_grid, 256, 0, stream>>>(adj_rows, adj_cols, adj_vals, BCUR,
                                            ADJ_RC, ADJ_V, N_ADJ);
    binC_adj<<<NB, 256, 0, stream>>>(BOFF, ADJ_RC, ADJ_V, ADJ_PAIR, ADJ_ROWPTR);

    // ---- x -> fp16 (XH overlays A1; rc dead after binC_adj) ----
    cvt16_kernel<<<(int)(usrN / 4 + 255) / 256, 256, 0, stream>>>(UR, XH, (int)(usrN / 4));
    cvt16_kernel<<<(int)(itmN / 4 + 255) / 256, 256, 0, stream>>>(ER, XH + usrN,
                                                                  (int)(itmN / 4));

    // ---- LGCN: x1 = adj@x -> X1H(fp16), out = x + x1; out = (out + adj@x1)/3 ----
    adj_spmm<0><<<N_UI / 4, 256, 0, stream>>>(ADJ_ROWPTR, ADJ_PAIR, XH, UR, ER, X1H, out);
    adj_spmm<1><<<N_UI / 4, 256, 0, stream>>>(ADJ_ROWPTR, ADJ_PAIR, X1H, nullptr, nullptr,
                                              nullptr, out);
}

// Round 9
// 510.927 us; speedup vs baseline: 1.8374x; 1.1237x over previous
//
#include <hip/hip_runtime.h>
#include <math.h>

#define N_USERS 50000
#define N_ITEMS 30000
#define N_ENTITIES 80000
#define N_UI (N_USERS + N_ITEMS)
#define D 64
#define N_KG_EDGES 2000000
#define N_INTERACT 1000000
#define N_ADJ 2000000
#define INV_TEMP 5.0f
#define EPS_PD 1e-6f
#define SHIFT 7         // bucket = key >> 7
#define NB 625          // 80000 / 128
#define BKEYS 128
#define BMASK 127
#define EPB 8192        // edges per binA/bhist block
#define BIG 1024        // binA/bhist block size

typedef _Float16 f16;

__device__ __forceinline__ float4 ld_h4(const f16* p) {
    struct h4 { f16 x, y, z, w; };
    h4 h = *(const h4*)p;
    return make_float4((float)h.x, (float)h.y, (float)h.z, (float)h.w);
}

__device__ __forceinline__ void st_h4(f16* p, float4 v) {
    struct h4 { f16 x, y, z, w; };
    h4 h = {(f16)v.x, (f16)v.y, (f16)v.z, (f16)v.w};
    *(h4*)p = h;
}

// ---- fp32 -> fp16 bulk convert (4 elems/thread) ----
__global__ void cvt16_kernel(const float* __restrict__ in, f16* __restrict__ outp, int n4) {
    int i = blockIdx.x * blockDim.x + threadIdx.x;
    if (i < n4) st_h4(outp + (size_t)i * 4, *(const float4*)(in + (size_t)i * 4));
}

// ---- bucket histogram, LDS-privatized; BIG threads ----
__global__ void bhist_kernel(const int* __restrict__ keys, int* __restrict__ bcnt, int n) {
    __shared__ int h[NB];
    for (int i = threadIdx.x; i < NB; i += BIG) h[i] = 0;
    __syncthreads();
    int e0 = blockIdx.x * EPB;
    int e1 = min(e0 + EPB, n);
    for (int e = e0 + (int)threadIdx.x; e < e1; e += BIG)
        atomicAdd(&h[keys[e] >> SHIFT], 1);
    __syncthreads();
    for (int i = threadIdx.x; i < NB; i += BIG)
        if (h[i]) atomicAdd(&bcnt[i], h[i]);
}

// ---- single-block scan over NB buckets: boff[0]=0, boff[i+1]=incl, bcur[i]=excl ----
__global__ void bscan_kernel(const int* __restrict__ cnt, int* __restrict__ boff,
                             int* __restrict__ bcur, int n) {
    __shared__ int wp[4];
    __shared__ int carry_s;
    int lane = threadIdx.x & 63, wv = threadIdx.x >> 6;
    if (threadIdx.x == 0) { carry_s = 0; boff[0] = 0; }
    __syncthreads();
    for (int base = 0; base < n; base += 256) {
        int i = base + (int)threadIdx.x;
        int v = (i < n) ? cnt[i] : 0;
        int x = v;
        #pragma unroll
        for (int o = 1; o < 64; o <<= 1) {
            int t = __shfl_up(x, o, 64);
            if (lane >= o) x += t;
        }
        if (lane == 63) wp[wv] = x;
        __syncthreads();
        int add = carry_s;
        for (int j = 0; j < wv; ++j) add += wp[j];
        int incl = x + add;
        if (i < n) { boff[i + 1] = incl; bcur[i] = incl - v; }
        __syncthreads();
        if (threadIdx.x == 255) carry_s = incl;
        __syncthreads();
    }
}

// ---- binA (KG): block counting sort; payload packed (tail<<7 | key) in ONE int ----
__global__ void binA_kg(const int* __restrict__ ei, int* __restrict__ bcur,
                        int* __restrict__ binned, int n) {
    __shared__ int hist[NB], base[NB];
    for (int i = threadIdx.x; i < NB; i += BIG) hist[i] = 0;
    __syncthreads();
    int e0 = blockIdx.x * EPB;
    for (int i = threadIdx.x; i < EPB; i += BIG) {
        int e = e0 + i;
        if (e < n) atomicAdd(&hist[ei[e] >> SHIFT], 1);
    }
    __syncthreads();
    for (int b = threadIdx.x; b < NB; b += BIG)
        base[b] = hist[b] ? atomicAdd(&bcur[b], hist[b]) : 0;
    __syncthreads();
    for (int i = threadIdx.x; i < NB; i += BIG) hist[i] = 0;
    __syncthreads();
    for (int i = threadIdx.x; i < EPB; i += BIG) {
        int e = e0 + i;
        if (e >= n) continue;
        int h = ei[e];
        int b = h >> SHIFT;
        int slot = base[b] + atomicAdd(&hist[b], 1);
        binned[slot] = (ei[n + e] << SHIFT) | (h & BMASK);
    }
}

// ---- binC (KG): per-bucket CSR rowptr + icnt + tails scatter (packed input) ----
__global__ void binC_kg(const int* __restrict__ boff, const int* __restrict__ binned,
                        int* __restrict__ tails, int* __restrict__ rowptr,
                        float* __restrict__ icnt) {
    __shared__ int cnt_s[BKEYS];
    __shared__ int cur_s[BKEYS];
    __shared__ int wp2[2];
    int b = blockIdx.x;
    int k0 = b << SHIFT;
    int s = boff[b], t = boff[b + 1];
    if (threadIdx.x < BKEYS) cnt_s[threadIdx.x] = 0;
    __syncthreads();
    for (int i = s + (int)threadIdx.x; i < t; i += 256)
        atomicAdd(&cnt_s[binned[i] & BMASK], 1);
    __syncthreads();
    int lane = threadIdx.x & 63, wv = threadIdx.x >> 6;
    int v = (threadIdx.x < BKEYS) ? cnt_s[threadIdx.x] : 0;
    int x = v;
    #pragma unroll
    for (int o = 1; o < 64; o <<= 1) {
        int tt = __shfl_up(x, o, 64);
        if (lane >= o) x += tt;
    }
    if (threadIdx.x < BKEYS && lane == 63) wp2[wv] = x;
    __syncthreads();
    int add = (wv == 1) ? wp2[0] : 0;
    int excl = s + (x - v) + add;
    if (threadIdx.x < BKEYS) {
        cur_s[threadIdx.x] = excl;
        rowptr[k0 + threadIdx.x] = excl;
        icnt[k0 + threadIdx.x] = 1.0f / fmaxf((float)v, 1.0f);
    }
    if (b == (int)gridDim.x - 1 && threadIdx.x == 0) rowptr[N_ENTITIES] = t;
    __syncthreads();
    for (int i = s + (int)threadIdx.x; i < t; i += 256) {
        int p = binned[i];
        int slot = atomicAdd(&cur_s[p & BMASK], 1);
        tails[slot] = (unsigned)p >> SHIFT;
    }
}

// ---- binA (adj): payload packed ((col<<7|key), valbits) int2 ----
__global__ void binA_adj(const int* __restrict__ rows, const int* __restrict__ cols,
                         const float* __restrict__ vals, int* __restrict__ bcur,
                         int2* __restrict__ rc, int n) {
    __shared__ int hist[NB], base[NB];
    for (int i = threadIdx.x; i < NB; i += BIG) hist[i] = 0;
    __syncthreads();
    int e0 = blockIdx.x * EPB;
    for (int i = threadIdx.x; i < EPB; i += BIG) {
        int e = e0 + i;
        if (e < n) atomicAdd(&hist[rows[e] >> SHIFT], 1);
    }
    __syncthreads();
    for (int b = threadIdx.x; b < NB; b += BIG)
        base[b] = hist[b] ? atomicAdd(&bcur[b], hist[b]) : 0;
    __syncthreads();
    for (int i = threadIdx.x; i < NB; i += BIG) hist[i] = 0;
    __syncthreads();
    for (int i = threadIdx.x; i < EPB; i += BIG) {
        int e = e0 + i;
        if (e >= n) continue;
        int r = rows[e];
        int b = r >> SHIFT;
        int slot = base[b] + atomicAdd(&hist[b], 1);
        rc[slot] = make_int2((cols[e] << SHIFT) | (r & BMASK), __float_as_int(vals[e]));
    }
}

// ---- binC (adj): per-bucket CSR rowptr + fused (col,val) scatter ----
__global__ void binC_adj(const int* __restrict__ boff, const int2* __restrict__ rc,
                         int2* __restrict__ pair, int* __restrict__ rowptr) {
    __shared__ int cnt_s[BKEYS];
    __shared__ int cur_s[BKEYS];
    __shared__ int wp2[2];
    int b = blockIdx.x;
    int k0 = b << SHIFT;
    int s = boff[b], t = boff[b + 1];
    if (threadIdx.x < BKEYS) cnt_s[threadIdx.x] = 0;
    __syncthreads();
    for (int i = s + (int)threadIdx.x; i < t; i += 256)
        atomicAdd(&cnt_s[rc[i].x & BMASK], 1);
    __syncthreads();
    int lane = threadIdx.x & 63, wv = threadIdx.x >> 6;
    int v = (threadIdx.x < BKEYS) ? cnt_s[threadIdx.x] : 0;
    int x = v;
    #pragma unroll
    for (int o = 1; o < 64; o <<= 1) {
        int tt = __shfl_up(x, o, 64);
        if (lane >= o) x += tt;
    }
    if (threadIdx.x < BKEYS && lane == 63) wp2[wv] = x;
    __syncthreads();
    int add = (wv == 1) ? wp2[0] : 0;
    int excl = s + (x - v) + add;
    if (threadIdx.x < BKEYS) {
        cur_s[threadIdx.x] = excl;
        rowptr[k0 + threadIdx.x] = excl;
    }
    if (b == (int)gridDim.x - 1 && threadIdx.x == 0) rowptr[N_UI] = t;
    __syncthreads();
    for (int i = s + (int)threadIdx.x; i < t; i += 256) {
        int2 p = rc[i];
        int slot = atomicAdd(&cur_s[p.x & BMASK], 1);
        pair[slot] = make_int2((unsigned)p.x >> SHIFT, p.y);
    }
}

// ---- per-user row offsets (interact_rows sorted) ----
__global__ void rowstart_kernel(const int* __restrict__ rows, int* __restrict__ rowstart) {
    int r = blockIdx.x * blockDim.x + threadIdx.x;
    if (r > N_USERS) return;
    int lo = 0, hi = N_INTERACT;
    while (lo < hi) {
        int mid = (lo + hi) >> 1;
        if (rows[mid] < r) lo = mid + 1; else hi = mid;
    }
    rowstart[r] = lo;
}

// ---- KG hop (fp32): gather + normalize + e_res(items) + SNORM ----
// FIRST: e_res base comes from ERI (all_embed items) instead of ER
template <bool FIRST>
__global__ void kg_hop(const int* __restrict__ rowptr, const int* __restrict__ tails,
                       const float* __restrict__ icnt, const float* __restrict__ Ain,
                       float* __restrict__ Aout, float* __restrict__ ER,
                       const float* __restrict__ ERI, float* __restrict__ snorm,
                       int nrows) {
    int wid = (blockIdx.x * blockDim.x + threadIdx.x) >> 6;
    int lane = threadIdx.x & 63;
    int g = lane >> 4, gl = lane & 15;
    if (wid >= nrows) return;
    int s = rowptr[wid], t = rowptr[wid + 1];
    float4 acc = {0.f, 0.f, 0.f, 0.f};
    int e = s + g;
    if (e < t) {
        int c = tails[e];
        float4 r = *(const float4*)(Ain + (size_t)c * D + gl * 4);
        int e2 = e + 4;
        int c2 = (e2 < t) ? tails[e2] : 0;
        while (true) {
            float4 r2 = {0.f, 0.f, 0.f, 0.f};
            if (e2 < t) r2 = *(const float4*)(Ain + (size_t)c2 * D + gl * 4);
            int e3 = e2 + 4;
            int c3 = (e3 < t) ? tails[e3] : 0;
            acc.x += r.x; acc.y += r.y; acc.z += r.z; acc.w += r.w;
            if (e2 >= t) break;
            e2 = e3; c2 = c3; r = r2;
        }
    }
    acc.x += __shfl_xor(acc.x, 16, 64); acc.x += __shfl_xor(acc.x, 32, 64);
    acc.y += __shfl_xor(acc.y, 16, 64); acc.y += __shfl_xor(acc.y, 32, 64);
    acc.z += __shfl_xor(acc.z, 16, 64); acc.z += __shfl_xor(acc.z, 32, 64);
    acc.w += __shfl_xor(acc.w, 16, 64); acc.w += __shfl_xor(acc.w, 32, 64);
    float ss = acc.x * acc.x + acc.y * acc.y + acc.z * acc.z + acc.w * acc.w;
    ss += __shfl_xor(ss, 1, 64); ss += __shfl_xor(ss, 2, 64);
    ss += __shfl_xor(ss, 4, 64); ss += __shfl_xor(ss, 8, 64);
    float nrm = fmaxf(sqrtf(ss), 1e-12f);
    float inv = 1.0f / nrm;
    if (g == 0) {
        size_t o = (size_t)wid * D + gl * 4;
        float4 ev = {acc.x * inv, acc.y * inv, acc.z * inv, acc.w * inv};
        *(float4*)(Aout + o) = ev;
        if (wid < N_ITEMS) {                 // e_res only consumed as [:N_ITEMS]
            float4 er = FIRST ? *(const float4*)(ERI + o) : *(const float4*)(ER + o);
            er.x += ev.x; er.y += ev.y; er.z += ev.z; er.w += ev.w;
            *(float4*)(ER + o) = er;
            if (gl == 0) snorm[wid] = nrm * icnt[wid];
        }
    }
}

// ---- per-user pipeline: mean pass + 4 independent online-softmax chains ----
// FIRST: u_res base read from URI (all_embed users) instead of UR
template <bool FIRST>
__global__ void user_hop(const float* __restrict__ E, const float* __restrict__ snorm,
                         const int* __restrict__ rowstart, const int* __restrict__ cols,
                         const float* __restrict__ vals, float* __restrict__ UR,
                         const float* __restrict__ URI) {
    int wid = (blockIdx.x * blockDim.x + threadIdx.x) >> 6;
    int lane = threadIdx.x & 63;
    int g = lane >> 4, gl = lane & 15;
    if (wid >= N_USERS) return;
    int s = rowstart[wid], t = rowstart[wid + 1];

    // pass A: user_mean (weighted), pipelined gather
    float4 mean = {0.f, 0.f, 0.f, 0.f};
    {
        int e = s + g;
        if (e < t) {
            int c = cols[e];
            float w = vals[e] * snorm[c];
            float4 r = *(const float4*)(E + (size_t)c * D + gl * 4);
            int e2 = e + 4;
            while (true) {
                float w2 = 0.f; float4 r2 = {0.f, 0.f, 0.f, 0.f};
                bool more = (e2 < t);
                if (more) {
                    int c2 = cols[e2];
                    w2 = vals[e2] * snorm[c2];
                    r2 = *(const float4*)(E + (size_t)c2 * D + gl * 4);
                }
                mean.x += w * r.x; mean.y += w * r.y;
                mean.z += w * r.z; mean.w += w * r.w;
                if (!more) break;
                w = w2; r = r2; e2 += 4;
            }
        }
    }
    mean.x += __shfl_xor(mean.x, 16, 64); mean.x += __shfl_xor(mean.x, 32, 64);
    mean.y += __shfl_xor(mean.y, 16, 64); mean.y += __shfl_xor(mean.y, 32, 64);
    mean.z += __shfl_xor(mean.z, 16, 64); mean.z += __shfl_xor(mean.z, 32, 64);
    mean.w += __shfl_xor(mean.w, 16, 64); mean.w += __shfl_xor(mean.w, 32, 64);

    // pass B: per-group online softmax, one-edge-ahead prefetch
    float m = -INFINITY, denom = 0.f;
    float4 acc = {0.f, 0.f, 0.f, 0.f};
    {
        int e = s + g;
        if (e < t) {
            int c = cols[e];
            float sn = snorm[c];
            float4 r = *(const float4*)(E + (size_t)c * D + gl * 4);
            int e2 = e + 4;
            while (true) {
                float sn2 = 0.f; float4 r2 = {0.f, 0.f, 0.f, 0.f};
                bool more = (e2 < t);
                if (more) {
                    int c2 = cols[e2];
                    sn2 = snorm[c2];
                    r2 = *(const float4*)(E + (size_t)c2 * D + gl * 4);
                }
                float4 il = {sn * r.x, sn * r.y, sn * r.z, sn * r.w};
                float dx = il.x - mean.x + EPS_PD;
                float dy = il.y - mean.y + EPS_PD;
                float dz = il.z - mean.z + EPS_PD;
                float dw = il.w - mean.w + EPS_PD;
                float ssl = dx * dx + dy * dy + dz * dz + dw * dw;
                ssl += __shfl_xor(ssl, 1, 64); ssl += __shfl_xor(ssl, 2, 64);
                ssl += __shfl_xor(ssl, 4, 64); ssl += __shfl_xor(ssl, 8, 64);
                float sc = sqrtf(ssl) * INV_TEMP;
                float m_new = fmaxf(m, sc);
                float scale = __expf(m - m_new);
                float ex = __expf(sc - m_new);
                denom = denom * scale + ex;
                acc.x = acc.x * scale + ex * il.x;
                acc.y = acc.y * scale + ex * il.y;
                acc.z = acc.z * scale + ex * il.z;
                acc.w = acc.w * scale + ex * il.w;
                m = m_new;
                if (!more) break;
                sn = sn2; r = r2; e2 += 4;
            }
        }
    }
    // merge 4 group states
    float mg = fmaxf(m, __shfl_xor(m, 16, 64));
    mg = fmaxf(mg, __shfl_xor(mg, 32, 64));
    float scl = __expf(fmaxf(m - mg, -88.0f));   // fmax eats NaN from (-inf)-(-inf)
    denom *= scl;
    acc.x *= scl; acc.y *= scl; acc.z *= scl; acc.w *= scl;
    denom += __shfl_xor(denom, 16, 64); denom += __shfl_xor(denom, 32, 64);
    acc.x += __shfl_xor(acc.x, 16, 64); acc.x += __shfl_xor(acc.x, 32, 64);
    acc.y += __shfl_xor(acc.y, 16, 64); acc.y += __shfl_xor(acc.y, 32, 64);
    acc.z += __shfl_xor(acc.z, 16, 64); acc.z += __shfl_xor(acc.z, 32, 64);
    acc.w += __shfl_xor(acc.w, 16, 64); acc.w += __shfl_xor(acc.w, 32, 64);
    float invd = denom > 0.f ? 1.0f / denom : 0.f;
    acc.x *= invd; acc.y *= invd; acc.z *= invd; acc.w *= invd;
    float ss = acc.x * acc.x + acc.y * acc.y + acc.z * acc.z + acc.w * acc.w;
    ss += __shfl_xor(ss, 1, 64); ss += __shfl_xor(ss, 2, 64);
    ss += __shfl_xor(ss, 4, 64); ss += __shfl_xor(ss, 8, 64);
    float inv = 1.0f / fmaxf(sqrtf(ss), 1e-12f);
    if (g == 0) {
        size_t o = (size_t)wid * D + gl * 4;
        float4 u = FIRST ? *(const float4*)(URI + o) : *(const float4*)(UR + o);
        u.x += acc.x * inv; u.y += acc.y * inv; u.z += acc.z * inv; u.w += acc.w * inv;
        *(float4*)(UR + o) = u;
    }
}

// ---- adj gather SpMM over fp16 rows; fp32 epilogues ----
__device__ __forceinline__ const float* xrow32(const float* U, const float* I, int c) {
    return (c < N_USERS) ? (U + (size_t)c * D) : (I + (size_t)(c - N_USERS) * D);
}

template <int MODE>
__global__ void adj_spmm(const int* __restrict__ rowptr, const int2* __restrict__ pair,
                         const f16* __restrict__ X, const float* __restrict__ XAU,
                         const float* __restrict__ XAI, f16* __restrict__ Y,
                         float* __restrict__ out) {
    int wid = (blockIdx.x * blockDim.x + threadIdx.x) >> 6;
    int lane = threadIdx.x & 63;
    int g = lane >> 4, gl = lane & 15;
    if (wid >= N_UI) return;
    int s = rowptr[wid], t = rowptr[wid + 1];
    float4 acc = {0.f, 0.f, 0.f, 0.f};
    int e = s + g;
    if (e < t) {
        int2 p = pair[e];
        float4 r = ld_h4(X + (size_t)p.x * D + gl * 4);
        int e2 = e + 4;
        int2 p2 = (e2 < t) ? pair[e2] : make_int2(0, 0);
        while (true) {
            float4 r2 = {0.f, 0.f, 0.f, 0.f};
            if (e2 < t) r2 = ld_h4(X + (size_t)p2.x * D + gl * 4);
            int e3 = e2 + 4;
            int2 p3 = (e3 < t) ? pair[e3] : make_int2(0, 0);
            float v = __int_as_float(p.y);
            acc.x += v * r.x; acc.y += v * r.y; acc.z += v * r.z; acc.w += v * r.w;
            if (e2 >= t) break;
            e2 = e3; p = p2; p2 = p3; r = r2;
        }
    }
    acc.x += __shfl_xor(acc.x, 16, 64); acc.x += __shfl_xor(acc.x, 32, 64);
    acc.y += __shfl_xor(acc.y, 16, 64); acc.y += __shfl_xor(acc.y, 32, 64);
    acc.z += __shfl_xor(acc.z, 16, 64); acc.z += __shfl_xor(acc.z, 32, 64);
    acc.w += __shfl_xor(acc.w, 16, 64); acc.w += __shfl_xor(acc.w, 32, 64);
    if (g == 0) {
        size_t o = (size_t)wid * D + gl * 4;
        if (MODE == 0) {
            st_h4(Y + o, acc);
            const float4 xa = *(const float4*)(xrow32(XAU, XAI, wid) + gl * 4);
            float4 ov = {xa.x + acc.x, xa.y + acc.y, xa.z + acc.z, xa.w + acc.w};
            *(float4*)(out + o) = ov;
        } else {
            float4 ov = *(const float4*)(out + o);
            ov.x = (ov.x + acc.x) * (1.0f / 3.0f);
            ov.y = (ov.y + acc.y) * (1.0f / 3.0f);
            ov.z = (ov.z + acc.z) * (1.0f / 3.0f);
            ov.w = (ov.w + acc.w) * (1.0f / 3.0f);
            *(float4*)(out + o) = ov;
        }
    }
}

extern "C" void kernel_launch(void* const* d_in, const int* in_sizes, int n_in,
                              void* d_out, int out_size, void* d_ws, size_t ws_size,
                              hipStream_t stream) {
    const float* all_embed     = (const float*)d_in[0];
    const float* interact_vals = (const float*)d_in[1];
    const float* adj_vals      = (const float*)d_in[2];
    const int*   edge_index    = (const int*)d_in[3];
    // d_in[4] = edge_type (unused)
    const int*   interact_rows = (const int*)d_in[5];
    const int*   interact_cols = (const int*)d_in[6];
    const int*   adj_rows      = (const int*)d_in[7];
    const int*   adj_cols      = (const int*)d_in[8];
    float* out = (float*)d_out;

    const size_t entN = (size_t)N_ENTITIES * D;   // 5,120,000
    const size_t usrN = (size_t)N_USERS * D;      // 3,200,000
    const size_t itmN = (size_t)N_ITEMS * D;      // 1,920,000

    float* cur = (float*)d_ws;
    float* UR = cur; cur += usrN;                 // u_res fp32
    float* ER = cur; cur += itmN;                 // e_res items fp32
    float* A0 = cur; cur += entN;                 // entity pong / later adj CSR
    float* A1 = cur; cur += entN;                 // kg-binned / entity ping / rc / XH,X1H
    int* KG_TAIL = (int*)cur; cur += N_KG_EDGES;  // KG CSR tails
    float* ICNT  = cur; cur += N_ENTITIES;
    float* SNORM = cur; cur += N_ITEMS + 16;
    int* KG_ROWPTR = (int*)cur;                    // N_ENTITIES+1 (+pad)
    int* BCNT      = KG_ROWPTR + N_ENTITIES + 2;   // NB
    int* BOFF      = BCNT + NB + 1;                // NB+1
    int* BCUR      = BOFF + NB + 2;                // NB
    int* ROWSTART  = BCUR + NB + 1;                // N_USERS+1

    // overlays (timeline-disjoint)
    int*  KG_BIN = (int*)A1;                       // packed ints; dead before kg_hop1 writes A1
    int*  ADJ_ROWPTR = (int*)A0;                   // A0 dead after hop-2 user_hop
    int2* ADJ_PAIR   = (int2*)(ADJ_ROWPTR + N_UI + 2);  // even offset -> 8B aligned
    int2* ADJ_RC = (int2*)A1;                      // A1 dead after hop-2 kg_hop reads it
    f16* XH  = (f16*)A1;                           // after binC_adj, rc dead
    f16* X1H = XH + (size_t)N_UI * D;

    const int grid_ep = (N_KG_EDGES + EPB - 1) / EPB;   // 245 (same for adj)

    // ---- KG CSR build: bucket-hist -> bucket-scan -> binA -> binC(rowptr+icnt) ----
    hipMemsetAsync(BCNT, 0, NB * sizeof(int), stream);
    bhist_kernel<<<grid_ep, BIG, 0, stream>>>(edge_index, BCNT, N_KG_EDGES);
    bscan_kernel<<<1, 256, 0, stream>>>(BCNT, BOFF, BCUR, NB);
    binA_kg<<<grid_ep, BIG, 0, stream>>>(edge_index, BCUR, KG_BIN, N_KG_EDGES);
    binC_kg<<<NB, 256, 0, stream>>>(BOFF, KG_BIN, KG_TAIL, KG_ROWPTR, ICNT);
    rowstart_kernel<<<(N_USERS + 256) / 256, 256, 0, stream>>>(interact_rows, ROWSTART);

    // ---- KG hops (hop 1 reads all_embed directly; residual bases fused) ----
    kg_hop<true><<<N_ENTITIES / 4, 256, 0, stream>>>(KG_ROWPTR, KG_TAIL, ICNT,
                                                     all_embed + usrN, A1, ER,
                                                     all_embed + usrN, SNORM, N_ENTITIES);
    user_hop<true><<<N_USERS / 4, 256, 0, stream>>>(A1, SNORM, ROWSTART, interact_cols,
                                                    interact_vals, UR, all_embed);
    kg_hop<false><<<N_ITEMS / 4, 256, 0, stream>>>(KG_ROWPTR, KG_TAIL, ICNT, A1, A0, ER,
                                                   nullptr, SNORM, N_ITEMS);
    user_hop<false><<<N_USERS / 4, 256, 0, stream>>>(A0, SNORM, ROWSTART, interact_cols,
                                                     interact_vals, UR, nullptr);

    // ---- adj CSR build (A0, A1 now dead) ----
    hipMemsetAsync(BCNT, 0, NB * sizeof(int), stream);
    bhist_kernel<<<grid_ep, BIG, 0, stream>>>(adj_rows, BCNT, N_ADJ);
    bscan_kernel<<<1, 256, 0, stream>>>(BCNT, BOFF, BCUR, NB);
    binA_adj<<<grid_ep, BIG, 0, stream>>>(adj_rows, adj_cols, adj_vals, BCUR,
                                          ADJ_RC, N_ADJ);
    binC_adj<<<NB, 256, 0, stream>>>(BOFF, ADJ_RC, ADJ_PAIR, ADJ_ROWPTR);

    // ---- x -> fp16 (XH overlays A1; rc dead after binC_adj) ----
    cvt16_kernel<<<(int)(usrN / 4 + 255) / 256, 256, 0, stream>>>(UR, XH, (int)(usrN / 4));
    cvt16_kernel<<<(int)(itmN / 4 + 255) / 256, 256, 0, stream>>>(ER, XH + usrN,
                                                                  (int)(itmN / 4));

    // ---- LGCN: x1 = adj@x -> X1H(fp16), out = x + x1; out = (out + adj@x1)/3 ----
    adj_spmm<0><<<N_UI / 4, 256, 0, stream>>>(ADJ_ROWPTR, ADJ_PAIR, XH, UR, ER, X1H, out);
    adj_spmm<1><<<N_UI / 4, 256, 0, stream>>>(ADJ_ROWPTR, ADJ_PAIR, X1H, nullptr, nullptr,
                                              nullptr, out);
}

// Round 10
// 470.938 us; speedup vs baseline: 1.9934x; 1.0849x over previous
//
#include <hip/hip_runtime.h>
#include <math.h>

#define N_USERS 50000
#define N_ITEMS 30000
#define N_ENTITIES 80000
#define N_UI (N_USERS + N_ITEMS)
#define D 64
#define N_KG_EDGES 2000000
#define N_INTERACT 1000000
#define N_ADJ 2000000
#define INV_TEMP 5.0f
#define EPS_PD 1e-6f
#define SHIFT 7         // bucket = key >> 7
#define NB 625          // 80000 / 128
#define BKEYS 128
#define BMASK 127
#define EPB 8192        // edges per binA/bhist block
#define BIG 1024        // binA/bhist block size
#define GRID_EP 245     // (2M + EPB-1)/EPB
#define UH_GRID 12500   // N_USERS/4
#define KG2_GRID 7500   // N_ITEMS/4
#define CVT_GRID 1875   // itmN/4/256

typedef _Float16 f16;

__device__ __forceinline__ float4 ld_h4(const f16* p) {
    struct h4 { f16 x, y, z, w; };
    h4 h = *(const h4*)p;
    return make_float4((float)h.x, (float)h.y, (float)h.z, (float)h.w);
}

__device__ __forceinline__ void st_h4(f16* p, float4 v) {
    struct h4 { f16 x, y, z, w; };
    h4 h = {(f16)v.x, (f16)v.y, (f16)v.z, (f16)v.w};
    *(h4*)p = h;
}

// ==== stage 1: bucket histograms (KG + adj) + rowstart binary search ====
__global__ void bhist_plus(const int* __restrict__ kg_ei, const int* __restrict__ adj_r,
                           const int* __restrict__ irows, int* __restrict__ bcntK,
                           int* __restrict__ bcntA, int* __restrict__ rowstart) {
    __shared__ int h[NB];
    int bb = blockIdx.x;
    if (bb < 2 * GRID_EP) {
        bool kg = bb < GRID_EP;
        const int* keys = kg ? kg_ei : adj_r;
        int* bcnt = kg ? bcntK : bcntA;
        int blk = kg ? bb : bb - GRID_EP;
        int n = kg ? N_KG_EDGES : N_ADJ;
        for (int i = threadIdx.x; i < NB; i += BIG) h[i] = 0;
        __syncthreads();
        int e0 = blk * EPB, e1 = min(e0 + EPB, n);
        for (int e = e0 + (int)threadIdx.x; e < e1; e += BIG)
            atomicAdd(&h[keys[e] >> SHIFT], 1);
        __syncthreads();
        for (int i = threadIdx.x; i < NB; i += BIG)
            if (h[i]) atomicAdd(&bcnt[i], h[i]);
    } else {
        int r = (bb - 2 * GRID_EP) * BIG + threadIdx.x;
        if (r > N_USERS) return;
        int lo = 0, hi = N_INTERACT;
        while (lo < hi) {
            int mid = (lo + hi) >> 1;
            if (irows[mid] < r) lo = mid + 1; else hi = mid;
        }
        rowstart[r] = lo;
    }
}

// ==== stage 2: scan both bucket arrays (block 0 = KG, block 1 = adj) ====
__global__ void bscan_both(const int* __restrict__ cntK, int* __restrict__ boffK,
                           int* __restrict__ bcurK, const int* __restrict__ cntA,
                           int* __restrict__ boffA, int* __restrict__ bcurA) {
    __shared__ int wp[4];
    __shared__ int carry_s;
    const int* cnt = blockIdx.x ? cntA : cntK;
    int* boff = blockIdx.x ? boffA : boffK;
    int* bcur = blockIdx.x ? bcurA : bcurK;
    int lane = threadIdx.x & 63, wv = threadIdx.x >> 6;
    if (threadIdx.x == 0) { carry_s = 0; boff[0] = 0; }
    __syncthreads();
    for (int base = 0; base < NB; base += 256) {
        int i = base + (int)threadIdx.x;
        int v = (i < NB) ? cnt[i] : 0;
        int x = v;
        #pragma unroll
        for (int o = 1; o < 64; o <<= 1) {
            int t = __shfl_up(x, o, 64);
            if (lane >= o) x += t;
        }
        if (lane == 63) wp[wv] = x;
        __syncthreads();
        int add = carry_s;
        for (int j = 0; j < wv; ++j) add += wp[j];
        int incl = x + add;
        if (i < NB) { boff[i + 1] = incl; bcur[i] = incl - v; }
        __syncthreads();
        if (threadIdx.x == 255) carry_s = incl;
        __syncthreads();
    }
}

// ==== stage 3: binA both (KG packed int; adj packed int2) ====
__global__ void binA_both(const int* __restrict__ kg_ei, int* __restrict__ bcurK,
                          int* __restrict__ kg_bin, const int* __restrict__ adj_r,
                          const int* __restrict__ adj_c, const float* __restrict__ adj_v,
                          int* __restrict__ bcurA, int2* __restrict__ rc) {
    __shared__ int hist[NB], base[NB];
    bool kg = blockIdx.x < GRID_EP;
    int blk = kg ? blockIdx.x : blockIdx.x - GRID_EP;
    int n = kg ? N_KG_EDGES : N_ADJ;
    int* bcur = kg ? bcurK : bcurA;
    const int* keys = kg ? kg_ei : adj_r;
    for (int i = threadIdx.x; i < NB; i += BIG) hist[i] = 0;
    __syncthreads();
    int e0 = blk * EPB;
    for (int i = threadIdx.x; i < EPB; i += BIG) {
        int e = e0 + i;
        if (e < n) atomicAdd(&hist[keys[e] >> SHIFT], 1);
    }
    __syncthreads();
    for (int b = threadIdx.x; b < NB; b += BIG)
        base[b] = hist[b] ? atomicAdd(&bcur[b], hist[b]) : 0;
    __syncthreads();
    for (int i = threadIdx.x; i < NB; i += BIG) hist[i] = 0;
    __syncthreads();
    for (int i = threadIdx.x; i < EPB; i += BIG) {
        int e = e0 + i;
        if (e >= n) continue;
        int k = keys[e];
        int b = k >> SHIFT;
        int slot = base[b] + atomicAdd(&hist[b], 1);
        if (kg) kg_bin[slot] = (kg_ei[n + e] << SHIFT) | (k & BMASK);
        else    rc[slot] = make_int2((adj_c[e] << SHIFT) | (k & BMASK),
                                     __float_as_int(adj_v[e]));
    }
}

// ==== stage 4: binC both (per-bucket CSR rowptr + scatter) ====
__global__ void binC_both(const int* __restrict__ boffK, const int* __restrict__ kg_bin,
                          int* __restrict__ tails, int* __restrict__ rowptrK,
                          float* __restrict__ icnt, const int* __restrict__ boffA,
                          const int2* __restrict__ rc, int2* __restrict__ pair,
                          int* __restrict__ rowptrA) {
    __shared__ int cnt_s[BKEYS];
    __shared__ int cur_s[BKEYS];
    __shared__ int wp2[2];
    bool kg = blockIdx.x < NB;
    int b = kg ? blockIdx.x : blockIdx.x - NB;
    const int* boff = kg ? boffK : boffA;
    int k0 = b << SHIFT;
    int s = boff[b], t = boff[b + 1];
    if (threadIdx.x < BKEYS) cnt_s[threadIdx.x] = 0;
    __syncthreads();
    for (int i = s + (int)threadIdx.x; i < t; i += 256)
        atomicAdd(&cnt_s[(kg ? kg_bin[i] : rc[i].x) & BMASK], 1);
    __syncthreads();
    int lane = threadIdx.x & 63, wv = threadIdx.x >> 6;
    int v = (threadIdx.x < BKEYS) ? cnt_s[threadIdx.x] : 0;
    int x = v;
    #pragma unroll
    for (int o = 1; o < 64; o <<= 1) {
        int tt = __shfl_up(x, o, 64);
        if (lane >= o) x += tt;
    }
    if (threadIdx.x < BKEYS && lane == 63) wp2[wv] = x;
    __syncthreads();
    int add = (wv == 1) ? wp2[0] : 0;
    int excl = s + (x - v) + add;
    if (threadIdx.x < BKEYS) {
        cur_s[threadIdx.x] = excl;
        if (kg) {
            rowptrK[k0 + threadIdx.x] = excl;
            icnt[k0 + threadIdx.x] = 1.0f / fmaxf((float)v, 1.0f);
        } else {
            rowptrA[k0 + threadIdx.x] = excl;
        }
    }
    if (threadIdx.x == 0 && b == NB - 1) {
        if (kg) rowptrK[N_ENTITIES] = t; else rowptrA[N_UI] = t;
    }
    __syncthreads();
    if (kg) {
        for (int i = s + (int)threadIdx.x; i < t; i += 256) {
            int p = kg_bin[i];
            int slot = atomicAdd(&cur_s[p & BMASK], 1);
            tails[slot] = (unsigned)p >> SHIFT;
        }
    } else {
        for (int i = s + (int)threadIdx.x; i < t; i += 256) {
            int2 p = rc[i];
            int slot = atomicAdd(&cur_s[p.x & BMASK], 1);
            pair[slot] = make_int2((unsigned)p.x >> SHIFT, p.y);
        }
    }
}

// ==== KG hop body (fp32): gather + normalize + e_res(items) + SNORM ====
template <bool FIRST>
__device__ __forceinline__ void kg_hop_body(
        int wid, const int* __restrict__ rowptr, const int* __restrict__ tails,
        const float* __restrict__ icnt, const float* __restrict__ Ain,
        float* __restrict__ Aout, float* __restrict__ ER,
        const float* __restrict__ ERI, float* __restrict__ snorm, int nrows) {
    int lane = threadIdx.x & 63;
    int g = lane >> 4, gl = lane & 15;
    if (wid >= nrows) return;
    int s = rowptr[wid], t = rowptr[wid + 1];
    float4 acc = {0.f, 0.f, 0.f, 0.f};
    int e = s + g;
    if (e < t) {
        int c = tails[e];
        float4 r = *(const float4*)(Ain + (size_t)c * D + gl * 4);
        int e2 = e + 4;
        int c2 = (e2 < t) ? tails[e2] : 0;
        while (true) {
            float4 r2 = {0.f, 0.f, 0.f, 0.f};
            if (e2 < t) r2 = *(const float4*)(Ain + (size_t)c2 * D + gl * 4);
            int e3 = e2 + 4;
            int c3 = (e3 < t) ? tails[e3] : 0;
            acc.x += r.x; acc.y += r.y; acc.z += r.z; acc.w += r.w;
            if (e2 >= t) break;
            e2 = e3; c2 = c3; r = r2;
        }
    }
    acc.x += __shfl_xor(acc.x, 16, 64); acc.x += __shfl_xor(acc.x, 32, 64);
    acc.y += __shfl_xor(acc.y, 16, 64); acc.y += __shfl_xor(acc.y, 32, 64);
    acc.z += __shfl_xor(acc.z, 16, 64); acc.z += __shfl_xor(acc.z, 32, 64);
    acc.w += __shfl_xor(acc.w, 16, 64); acc.w += __shfl_xor(acc.w, 32, 64);
    float ss = acc.x * acc.x + acc.y * acc.y + acc.z * acc.z + acc.w * acc.w;
    ss += __shfl_xor(ss, 1, 64); ss += __shfl_xor(ss, 2, 64);
    ss += __shfl_xor(ss, 4, 64); ss += __shfl_xor(ss, 8, 64);
    float nrm = fmaxf(sqrtf(ss), 1e-12f);
    float inv = 1.0f / nrm;
    if (g == 0) {
        size_t o = (size_t)wid * D + gl * 4;
        float4 ev = {acc.x * inv, acc.y * inv, acc.z * inv, acc.w * inv};
        *(float4*)(Aout + o) = ev;
        if (wid < N_ITEMS) {
            float4 er = FIRST ? *(const float4*)(ERI + o) : *(const float4*)(ER + o);
            er.x += ev.x; er.y += ev.y; er.z += ev.z; er.w += ev.w;
            *(float4*)(ER + o) = er;
            if (gl == 0) snorm[wid] = nrm * icnt[wid];
        }
    }
}

// ==== per-user body: mean pass + 4 independent online-softmax chains ====
template <bool FIRST>
__device__ __forceinline__ void user_hop_body(
        int wid, const float* __restrict__ E, const float* __restrict__ snorm,
        const int* __restrict__ rowstart, const int* __restrict__ cols,
        const float* __restrict__ vals, float* __restrict__ UR,
        const float* __restrict__ URI, f16* __restrict__ XHu) {
    int lane = threadIdx.x & 63;
    int g = lane >> 4, gl = lane & 15;
    if (wid >= N_USERS) return;
    int s = rowstart[wid], t = rowstart[wid + 1];

    float4 mean = {0.f, 0.f, 0.f, 0.f};
    {
        int e = s + g;
        if (e < t) {
            int c = cols[e];
            float w = vals[e] * snorm[c];
            float4 r = *(const float4*)(E + (size_t)c * D + gl * 4);
            int e2 = e + 4;
            while (true) {
                float w2 = 0.f; float4 r2 = {0.f, 0.f, 0.f, 0.f};
                bool more = (e2 < t);
                if (more) {
                    int c2 = cols[e2];
                    w2 = vals[e2] * snorm[c2];
                    r2 = *(const float4*)(E + (size_t)c2 * D + gl * 4);
                }
                mean.x += w * r.x; mean.y += w * r.y;
                mean.z += w * r.z; mean.w += w * r.w;
                if (!more) break;
                w = w2; r = r2; e2 += 4;
            }
        }
    }
    mean.x += __shfl_xor(mean.x, 16, 64); mean.x += __shfl_xor(mean.x, 32, 64);
    mean.y += __shfl_xor(mean.y, 16, 64); mean.y += __shfl_xor(mean.y, 32, 64);
    mean.z += __shfl_xor(mean.z, 16, 64); mean.z += __shfl_xor(mean.z, 32, 64);
    mean.w += __shfl_xor(mean.w, 16, 64); mean.w += __shfl_xor(mean.w, 32, 64);

    float m = -INFINITY, denom = 0.f;
    float4 acc = {0.f, 0.f, 0.f, 0.f};
    {
        int e = s + g;
        if (e < t) {
            int c = cols[e];
            float sn = snorm[c];
            float4 r = *(const float4*)(E + (size_t)c * D + gl * 4);
            int e2 = e + 4;
            while (true) {
                float sn2 = 0.f; float4 r2 = {0.f, 0.f, 0.f, 0.f};
                bool more = (e2 < t);
                if (more) {
                    int c2 = cols[e2];
                    sn2 = snorm[c2];
                    r2 = *(const float4*)(E + (size_t)c2 * D + gl * 4);
                }
                float4 il = {sn * r.x, sn * r.y, sn * r.z, sn * r.w};
                float dx = il.x - mean.x + EPS_PD;
                float dy = il.y - mean.y + EPS_PD;
                float dz = il.z - mean.z + EPS_PD;
                float dw = il.w - mean.w + EPS_PD;
                float ssl = dx * dx + dy * dy + dz * dz + dw * dw;
                ssl += __shfl_xor(ssl, 1, 64); ssl += __shfl_xor(ssl, 2, 64);
                ssl += __shfl_xor(ssl, 4, 64); ssl += __shfl_xor(ssl, 8, 64);
                float sc = sqrtf(ssl) * INV_TEMP;
                float m_new = fmaxf(m, sc);
                float scale = __expf(m - m_new);
                float ex = __expf(sc - m_new);
                denom = denom * scale + ex;
                acc.x = acc.x * scale + ex * il.x;
                acc.y = acc.y * scale + ex * il.y;
                acc.z = acc.z * scale + ex * il.z;
                acc.w = acc.w * scale + ex * il.w;
                m = m_new;
                if (!more) break;
                sn = sn2; r = r2; e2 += 4;
            }
        }
    }
    float mg = fmaxf(m, __shfl_xor(m, 16, 64));
    mg = fmaxf(mg, __shfl_xor(mg, 32, 64));
    float scl = __expf(fmaxf(m - mg, -88.0f));
    denom *= scl;
    acc.x *= scl; acc.y *= scl; acc.z *= scl; acc.w *= scl;
    denom += __shfl_xor(denom, 16, 64); denom += __shfl_xor(denom, 32, 64);
    acc.x += __shfl_xor(acc.x, 16, 64); acc.x += __shfl_xor(acc.x, 32, 64);
    acc.y += __shfl_xor(acc.y, 16, 64); acc.y += __shfl_xor(acc.y, 32, 64);
    acc.z += __shfl_xor(acc.z, 16, 64); acc.z += __shfl_xor(acc.z, 32, 64);
    acc.w += __shfl_xor(acc.w, 16, 64); acc.w += __shfl_xor(acc.w, 32, 64);
    float invd = denom > 0.f ? 1.0f / denom : 0.f;
    acc.x *= invd; acc.y *= invd; acc.z *= invd; acc.w *= invd;
    float ss = acc.x * acc.x + acc.y * acc.y + acc.z * acc.z + acc.w * acc.w;
    ss += __shfl_xor(ss, 1, 64); ss += __shfl_xor(ss, 2, 64);
    ss += __shfl_xor(ss, 4, 64); ss += __shfl_xor(ss, 8, 64);
    float inv = 1.0f / fmaxf(sqrtf(ss), 1e-12f);
    if (g == 0) {
        size_t o = (size_t)wid * D + gl * 4;
        float4 u = FIRST ? *(const float4*)(URI + o) : *(const float4*)(UR + o);
        u.x += acc.x * inv; u.y += acc.y * inv; u.z += acc.z * inv; u.w += acc.w * inv;
        *(float4*)(UR + o) = u;
        if (XHu) st_h4(XHu + o, u);
    }
}

// ==== hop-1 over all entities ====
__global__ void kg1_kernel(const int* __restrict__ rowptr, const int* __restrict__ tails,
                           const float* __restrict__ icnt, const float* __restrict__ Ain,
                           float* __restrict__ A1, float* __restrict__ ER,
                           const float* __restrict__ ERI, float* __restrict__ sn1) {
    int wid = (blockIdx.x * blockDim.x + threadIdx.x) >> 6;
    kg_hop_body<true>(wid, rowptr, tails, icnt, Ain, A1, ER, ERI, sn1, N_ENTITIES);
}

// ==== mid: user_hop1 (blocks < UH_GRID) || kg_hop2 (rest) — both read A1 ====
__global__ void mid_kernel(const float* __restrict__ A1, const float* __restrict__ sn1,
                           const int* __restrict__ rowstart, const int* __restrict__ cols,
                           const float* __restrict__ vals, float* __restrict__ UR,
                           const float* __restrict__ URI, const int* __restrict__ rowptr,
                           const int* __restrict__ tails, const float* __restrict__ icnt,
                           float* __restrict__ A0I, float* __restrict__ ER,
                           float* __restrict__ sn2) {
    if (blockIdx.x < UH_GRID) {
        int wid = (blockIdx.x * blockDim.x + threadIdx.x) >> 6;
        user_hop_body<true>(wid, A1, sn1, rowstart, cols, vals, UR, URI, nullptr);
    } else {
        int wid = (((blockIdx.x - UH_GRID) * blockDim.x) + threadIdx.x) >> 6;
        kg_hop_body<false>(wid, rowptr, tails, icnt, A1, A0I, ER, nullptr, sn2, N_ITEMS);
    }
}

// ==== fin: user_hop2 (+XH user part) || ER -> XH items cvt ====
__global__ void fin_kernel(const float* __restrict__ A0I, const float* __restrict__ sn2,
                           const int* __restrict__ rowstart, const int* __restrict__ cols,
                           const float* __restrict__ vals, float* __restrict__ UR,
                           f16* __restrict__ XH, const float* __restrict__ ER) {
    if (blockIdx.x < UH_GRID) {
        int wid = (blockIdx.x * blockDim.x + threadIdx.x) >> 6;
        user_hop_body<false>(wid, A0I, sn2, rowstart, cols, vals, UR, nullptr, XH);
    } else {
        int i = (blockIdx.x - UH_GRID) * blockDim.x + threadIdx.x;
        if (i < (N_ITEMS * D) / 4)
            st_h4(XH + (size_t)N_USERS * D + (size_t)i * 4,
                  *(const float4*)(ER + (size_t)i * 4));
    }
}

// ==== adj gather SpMM over fp16 rows; fp32 epilogues ====
__device__ __forceinline__ const float* xrow32(const float* U, const float* I, int c) {
    return (c < N_USERS) ? (U + (size_t)c * D) : (I + (size_t)(c - N_USERS) * D);
}

template <int MODE>
__global__ void adj_spmm(const int* __restrict__ rowptr, const int2* __restrict__ pair,
                         const f16* __restrict__ X, const float* __restrict__ XAU,
                         const float* __restrict__ XAI, f16* __restrict__ Y,
                         float* __restrict__ out) {
    int wid = (blockIdx.x * blockDim.x + threadIdx.x) >> 6;
    int lane = threadIdx.x & 63;
    int g = lane >> 4, gl = lane & 15;
    if (wid >= N_UI) return;
    int s = rowptr[wid], t = rowptr[wid + 1];
    float4 acc = {0.f, 0.f, 0.f, 0.f};
    int e = s + g;
    if (e < t) {
        int2 p = pair[e];
        float4 r = ld_h4(X + (size_t)p.x * D + gl * 4);
        int e2 = e + 4;
        int2 p2 = (e2 < t) ? pair[e2] : make_int2(0, 0);
        while (true) {
            float4 r2 = {0.f, 0.f, 0.f, 0.f};
            if (e2 < t) r2 = ld_h4(X + (size_t)p2.x * D + gl * 4);
            int e3 = e2 + 4;
            int2 p3 = (e3 < t) ? pair[e3] : make_int2(0, 0);
            float v = __int_as_float(p.y);
            acc.x += v * r.x; acc.y += v * r.y; acc.z += v * r.z; acc.w += v * r.w;
            if (e2 >= t) break;
            e2 = e3; p = p2; p2 = p3; r = r2;
        }
    }
    acc.x += __shfl_xor(acc.x, 16, 64); acc.x += __shfl_xor(acc.x, 32, 64);
    acc.y += __shfl_xor(acc.y, 16, 64); acc.y += __shfl_xor(acc.y, 32, 64);
    acc.z += __shfl_xor(acc.z, 16, 64); acc.z += __shfl_xor(acc.z, 32, 64);
    acc.w += __shfl_xor(acc.w, 16, 64); acc.w += __shfl_xor(acc.w, 32, 64);
    if (g == 0) {
        size_t o = (size_t)wid * D + gl * 4;
        if (MODE == 0) {
            st_h4(Y + o, acc);
            const float4 xa = *(const float4*)(xrow32(XAU, XAI, wid) + gl * 4);
            float4 ov = {xa.x + acc.x, xa.y + acc.y, xa.z + acc.z, xa.w + acc.w};
            *(float4*)(out + o) = ov;
        } else {
            float4 ov = *(const float4*)(out + o);
            ov.x = (ov.x + acc.x) * (1.0f / 3.0f);
            ov.y = (ov.y + acc.y) * (1.0f / 3.0f);
            ov.z = (ov.z + acc.z) * (1.0f / 3.0f);
            ov.w = (ov.w + acc.w) * (1.0f / 3.0f);
            *(float4*)(out + o) = ov;
        }
    }
}

extern "C" void kernel_launch(void* const* d_in, const int* in_sizes, int n_in,
                              void* d_out, int out_size, void* d_ws, size_t ws_size,
                              hipStream_t stream) {
    const float* all_embed     = (const float*)d_in[0];
    const float* interact_vals = (const float*)d_in[1];
    const float* adj_vals      = (const float*)d_in[2];
    const int*   edge_index    = (const int*)d_in[3];
    // d_in[4] = edge_type (unused)
    const int*   interact_rows = (const int*)d_in[5];
    const int*   interact_cols = (const int*)d_in[6];
    const int*   adj_rows      = (const int*)d_in[7];
    const int*   adj_cols      = (const int*)d_in[8];
    float* out = (float*)d_out;

    const size_t usrN = (size_t)N_USERS * D;      // 3,200,000
    const size_t itmN = (size_t)N_ITEMS * D;      // 1,920,000
    const size_t entN = (size_t)N_ENTITIES * D;   // 5,120,000

    float* cur = (float*)d_ws;
    float* UR  = cur; cur += usrN;                // u_res fp32 (KG_BIN overlays pre-hop)
    float* ER  = cur; cur += itmN;                // e_res items fp32
    float* A0I = cur; cur += itmN;                // hop-2 entity output, items only
    float* A1  = cur; cur += entN;                // hop-1 output (ADJ_RC pre / XH,X1H post)
    int* KG_TAIL = (int*)cur; cur += N_KG_EDGES;
    int2* ADJ_PAIR = (int2*)cur; cur += 2 * (size_t)N_ADJ;  // dedicated, 8B aligned
    float* ICNT   = cur; cur += N_ENTITIES;
    float* SNORM1 = cur; cur += N_ITEMS + 16;
    float* SNORM2 = cur; cur += N_ITEMS + 16;
    int* KG_ROWPTR  = (int*)cur;                   // N_ENTITIES+1 (+pad)
    int* ADJ_ROWPTR = KG_ROWPTR + N_ENTITIES + 2;  // N_UI+1 (+pad)
    int* BCNT_K     = ADJ_ROWPTR + N_UI + 2;       // NB  (BCNT_K/BCNT_A contiguous!)
    int* BCNT_A     = BCNT_K + NB;                 // NB
    int* BOFF_K     = BCNT_A + NB;                 // NB+1
    int* BOFF_A     = BOFF_K + NB + 1;             // NB+1
    int* BCUR_K     = BOFF_A + NB + 1;             // NB
    int* BCUR_A     = BCUR_K + NB;                 // NB
    int* ROWSTART   = BCUR_A + NB;                 // N_USERS+1

    // overlays (timeline-disjoint)
    int*  KG_BIN = (int*)UR;                       // binA..binC, before user_hop1 writes UR
    int2* ADJ_RC = (int2*)A1;                      // binA..binC, before kg1 writes A1
    f16*  XH  = (f16*)A1;                          // after mid (A1 dead post kg_hop2)
    f16*  X1H = XH + (size_t)N_UI * D;

    // ---- CSR builds (KG + adj fused stage-wise) ----
    hipMemsetAsync(BCNT_K, 0, 2 * NB * sizeof(int), stream);
    bhist_plus<<<2 * GRID_EP + 49, BIG, 0, stream>>>(edge_index, adj_rows, interact_rows,
                                                     BCNT_K, BCNT_A, ROWSTART);
    bscan_both<<<2, 256, 0, stream>>>(BCNT_K, BOFF_K, BCUR_K, BCNT_A, BOFF_A, BCUR_A);
    binA_both<<<2 * GRID_EP, BIG, 0, stream>>>(edge_index, BCUR_K, KG_BIN, adj_rows,
                                               adj_cols, adj_vals, BCUR_A, ADJ_RC);
    binC_both<<<2 * NB, 256, 0, stream>>>(BOFF_K, KG_BIN, KG_TAIL, KG_ROWPTR, ICNT,
                                          BOFF_A, ADJ_RC, ADJ_PAIR, ADJ_ROWPTR);

    // ---- KG hops: kg1 -> (user1 || kg2) -> (user2 || cvt-items) ----
    kg1_kernel<<<N_ENTITIES / 4, 256, 0, stream>>>(KG_ROWPTR, KG_TAIL, ICNT,
                                                   all_embed + usrN, A1, ER,
                                                   all_embed + usrN, SNORM1);
    mid_kernel<<<UH_GRID + KG2_GRID, 256, 0, stream>>>(A1, SNORM1, ROWSTART,
                                                       interact_cols, interact_vals,
                                                       UR, all_embed, KG_ROWPTR, KG_TAIL,
                                                       ICNT, A0I, ER, SNORM2);
    fin_kernel<<<UH_GRID + CVT_GRID, 256, 0, stream>>>(A0I, SNORM2, ROWSTART,
                                                       interact_cols, interact_vals,
                                                       UR, XH, ER);

    // ---- LGCN: x1 = adj@x -> X1H(fp16), out = x + x1; out = (out + adj@x1)/3 ----
    adj_spmm<0><<<N_UI / 4, 256, 0, stream>>>(ADJ_ROWPTR, ADJ_PAIR, XH, UR, ER, X1H, out);
    adj_spmm<1><<<N_UI / 4, 256, 0, stream>>>(ADJ_ROWPTR, ADJ_PAIR, X1H, nullptr, nullptr,
                                              nullptr, out);
}

// Round 11
// 415.222 us; speedup vs baseline: 2.2609x; 1.1342x over previous
//
#include <hip/hip_runtime.h>
#include <math.h>

#define N_USERS 50000
#define N_ITEMS 30000
#define N_ENTITIES 80000
#define N_UI (N_USERS + N_ITEMS)
#define D 64
#define N_KG_EDGES 2000000
#define N_INTERACT 1000000
#define N_ADJ 2000000
#define INV_TEMP 5.0f
#define EPS_PD 1e-6f
#define SHIFT 7         // bucket = key >> 7
#define NB 625          // 80000 / 128
#define BKEYS 128
#define BMASK 127
#define EPB 8192        // edges per binA/bhist block
#define BIG 1024        // binA/bhist block size
#define GRID_EP 245     // (2M + EPB-1)/EPB
#define UH_GRID 12500   // N_USERS/4
#define KG2_GRID 7500   // N_ITEMS/4
#define CVT_GRID 1875   // itmN/4/256

typedef _Float16 f16;

__device__ __forceinline__ float4 ld_h4(const f16* p) {
    struct h4 { f16 x, y, z, w; };
    h4 h = *(const h4*)p;
    return make_float4((float)h.x, (float)h.y, (float)h.z, (float)h.w);
}

__device__ __forceinline__ void st_h4(f16* p, float4 v) {
    struct h4 { f16 x, y, z, w; };
    h4 h = {(f16)v.x, (f16)v.y, (f16)v.z, (f16)v.w};
    *(h4*)p = h;
}

// ==== stage 1: bucket histograms (KG + adj) + rowstart binary search ====
__global__ void bhist_plus(const int* __restrict__ kg_ei, const int* __restrict__ adj_r,
                           const int* __restrict__ irows, int* __restrict__ bcntK,
                           int* __restrict__ bcntA, int* __restrict__ rowstart) {
    __shared__ int h[NB];
    int bb = blockIdx.x;
    if (bb < 2 * GRID_EP) {
        bool kg = bb < GRID_EP;
        const int* keys = kg ? kg_ei : adj_r;
        int* bcnt = kg ? bcntK : bcntA;
        int blk = kg ? bb : bb - GRID_EP;
        int n = kg ? N_KG_EDGES : N_ADJ;
        for (int i = threadIdx.x; i < NB; i += BIG) h[i] = 0;
        __syncthreads();
        int e0 = blk * EPB, e1 = min(e0 + EPB, n);
        for (int e = e0 + (int)threadIdx.x; e < e1; e += BIG)
            atomicAdd(&h[keys[e] >> SHIFT], 1);
        __syncthreads();
        for (int i = threadIdx.x; i < NB; i += BIG)
            if (h[i]) atomicAdd(&bcnt[i], h[i]);
    } else {
        int r = (bb - 2 * GRID_EP) * BIG + threadIdx.x;
        if (r > N_USERS) return;
        int lo = 0, hi = N_INTERACT;
        while (lo < hi) {
            int mid = (lo + hi) >> 1;
            if (irows[mid] < r) lo = mid + 1; else hi = mid;
        }
        rowstart[r] = lo;
    }
}

// ==== stage 2: scan both bucket arrays (block 0 = KG, block 1 = adj) ====
__global__ void bscan_both(const int* __restrict__ cntK, int* __restrict__ boffK,
                           int* __restrict__ bcurK, const int* __restrict__ cntA,
                           int* __restrict__ boffA, int* __restrict__ bcurA) {
    __shared__ int wp[4];
    __shared__ int carry_s;
    const int* cnt = blockIdx.x ? cntA : cntK;
    int* boff = blockIdx.x ? boffA : boffK;
    int* bcur = blockIdx.x ? bcurA : bcurK;
    int lane = threadIdx.x & 63, wv = threadIdx.x >> 6;
    if (threadIdx.x == 0) { carry_s = 0; boff[0] = 0; }
    __syncthreads();
    for (int base = 0; base < NB; base += 256) {
        int i = base + (int)threadIdx.x;
        int v = (i < NB) ? cnt[i] : 0;
        int x = v;
        #pragma unroll
        for (int o = 1; o < 64; o <<= 1) {
            int t = __shfl_up(x, o, 64);
            if (lane >= o) x += t;
        }
        if (lane == 63) wp[wv] = x;
        __syncthreads();
        int add = carry_s;
        for (int j = 0; j < wv; ++j) add += wp[j];
        int incl = x + add;
        if (i < NB) { boff[i + 1] = incl; bcur[i] = incl - v; }
        __syncthreads();
        if (threadIdx.x == 255) carry_s = incl;
        __syncthreads();
    }
}

// ==== stage 3: binA both (KG packed int; adj packed int2) ====
__global__ void binA_both(const int* __restrict__ kg_ei, int* __restrict__ bcurK,
                          int* __restrict__ kg_bin, const int* __restrict__ adj_r,
                          const int* __restrict__ adj_c, const float* __restrict__ adj_v,
                          int* __restrict__ bcurA, int2* __restrict__ rc) {
    __shared__ int hist[NB], base[NB];
    bool kg = blockIdx.x < GRID_EP;
    int blk = kg ? blockIdx.x : blockIdx.x - GRID_EP;
    int n = kg ? N_KG_EDGES : N_ADJ;
    int* bcur = kg ? bcurK : bcurA;
    const int* keys = kg ? kg_ei : adj_r;
    for (int i = threadIdx.x; i < NB; i += BIG) hist[i] = 0;
    __syncthreads();
    int e0 = blk * EPB;
    for (int i = threadIdx.x; i < EPB; i += BIG) {
        int e = e0 + i;
        if (e < n) atomicAdd(&hist[keys[e] >> SHIFT], 1);
    }
    __syncthreads();
    for (int b = threadIdx.x; b < NB; b += BIG)
        base[b] = hist[b] ? atomicAdd(&bcur[b], hist[b]) : 0;
    __syncthreads();
    for (int i = threadIdx.x; i < NB; i += BIG) hist[i] = 0;
    __syncthreads();
    for (int i = threadIdx.x; i < EPB; i += BIG) {
        int e = e0 + i;
        if (e >= n) continue;
        int k = keys[e];
        int b = k >> SHIFT;
        int slot = base[b] + atomicAdd(&hist[b], 1);
        if (kg) kg_bin[slot] = (kg_ei[n + e] << SHIFT) | (k & BMASK);
        else    rc[slot] = make_int2((adj_c[e] << SHIFT) | (k & BMASK),
                                     __float_as_int(adj_v[e]));
    }
}

// ==== stage 4: binC both (per-bucket CSR rowptr + scatter) ====
__global__ void binC_both(const int* __restrict__ boffK, const int* __restrict__ kg_bin,
                          int* __restrict__ tails, int* __restrict__ rowptrK,
                          float* __restrict__ icnt, const int* __restrict__ boffA,
                          const int2* __restrict__ rc, int2* __restrict__ pair,
                          int* __restrict__ rowptrA) {
    __shared__ int cnt_s[BKEYS];
    __shared__ int cur_s[BKEYS];
    __shared__ int wp2[2];
    bool kg = blockIdx.x < NB;
    int b = kg ? blockIdx.x : blockIdx.x - NB;
    const int* boff = kg ? boffK : boffA;
    int k0 = b << SHIFT;
    int s = boff[b], t = boff[b + 1];
    if (threadIdx.x < BKEYS) cnt_s[threadIdx.x] = 0;
    __syncthreads();
    for (int i = s + (int)threadIdx.x; i < t; i += 256)
        atomicAdd(&cnt_s[(kg ? kg_bin[i] : rc[i].x) & BMASK], 1);
    __syncthreads();
    int lane = threadIdx.x & 63, wv = threadIdx.x >> 6;
    int v = (threadIdx.x < BKEYS) ? cnt_s[threadIdx.x] : 0;
    int x = v;
    #pragma unroll
    for (int o = 1; o < 64; o <<= 1) {
        int tt = __shfl_up(x, o, 64);
        if (lane >= o) x += tt;
    }
    if (threadIdx.x < BKEYS && lane == 63) wp2[wv] = x;
    __syncthreads();
    int add = (wv == 1) ? wp2[0] : 0;
    int excl = s + (x - v) + add;
    if (threadIdx.x < BKEYS) {
        cur_s[threadIdx.x] = excl;
        if (kg) {
            rowptrK[k0 + threadIdx.x] = excl;
            icnt[k0 + threadIdx.x] = 1.0f / fmaxf((float)v, 1.0f);
        } else {
            rowptrA[k0 + threadIdx.x] = excl;
        }
    }
    if (threadIdx.x == 0 && b == NB - 1) {
        if (kg) rowptrK[N_ENTITIES] = t; else rowptrA[N_UI] = t;
    }
    __syncthreads();
    if (kg) {
        for (int i = s + (int)threadIdx.x; i < t; i += 256) {
            int p = kg_bin[i];
            int slot = atomicAdd(&cur_s[p & BMASK], 1);
            tails[slot] = (unsigned)p >> SHIFT;
        }
    } else {
        for (int i = s + (int)threadIdx.x; i < t; i += 256) {
            int2 p = rc[i];
            int slot = atomicAdd(&cur_s[p.x & BMASK], 1);
            pair[slot] = make_int2((unsigned)p.x >> SHIFT, p.y);
        }
    }
}

// ==== KG hop body (fp32): 4-wide chunked gather + normalize + e_res + SNORM ====
template <bool FIRST>
__device__ __forceinline__ void kg_hop_body(
        int wid, const int* __restrict__ rowptr, const int* __restrict__ tails,
        const float* __restrict__ icnt, const float* __restrict__ Ain,
        float* __restrict__ Aout, float* __restrict__ ER,
        const float* __restrict__ ERI, float* __restrict__ snorm, int nrows) {
    int lane = threadIdx.x & 63;
    int g = lane >> 4, gl = lane & 15;
    if (wid >= nrows) return;
    int s = rowptr[wid], t = rowptr[wid + 1];
    float4 acc = {0.f, 0.f, 0.f, 0.f};
    for (int e = s + g; e < t; e += 16) {
        int e1 = e + 4, e2 = e + 8, e3 = e + 12;
        int c0 = tails[e];
        int c1 = (e1 < t) ? tails[e1] : 0;
        int c2 = (e2 < t) ? tails[e2] : 0;
        int c3 = (e3 < t) ? tails[e3] : 0;
        float4 r0 = *(const float4*)(Ain + (size_t)c0 * D + gl * 4);
        float4 r1 = {0.f, 0.f, 0.f, 0.f};
        float4 r2 = {0.f, 0.f, 0.f, 0.f};
        float4 r3 = {0.f, 0.f, 0.f, 0.f};
        if (e1 < t) r1 = *(const float4*)(Ain + (size_t)c1 * D + gl * 4);
        if (e2 < t) r2 = *(const float4*)(Ain + (size_t)c2 * D + gl * 4);
        if (e3 < t) r3 = *(const float4*)(Ain + (size_t)c3 * D + gl * 4);
        acc.x += (r0.x + r1.x) + (r2.x + r3.x);
        acc.y += (r0.y + r1.y) + (r2.y + r3.y);
        acc.z += (r0.z + r1.z) + (r2.z + r3.z);
        acc.w += (r0.w + r1.w) + (r2.w + r3.w);
    }
    acc.x += __shfl_xor(acc.x, 16, 64); acc.x += __shfl_xor(acc.x, 32, 64);
    acc.y += __shfl_xor(acc.y, 16, 64); acc.y += __shfl_xor(acc.y, 32, 64);
    acc.z += __shfl_xor(acc.z, 16, 64); acc.z += __shfl_xor(acc.z, 32, 64);
    acc.w += __shfl_xor(acc.w, 16, 64); acc.w += __shfl_xor(acc.w, 32, 64);
    float ss = acc.x * acc.x + acc.y * acc.y + acc.z * acc.z + acc.w * acc.w;
    ss += __shfl_xor(ss, 1, 64); ss += __shfl_xor(ss, 2, 64);
    ss += __shfl_xor(ss, 4, 64); ss += __shfl_xor(ss, 8, 64);
    float nrm = fmaxf(sqrtf(ss), 1e-12f);
    float inv = 1.0f / nrm;
    if (g == 0) {
        size_t o = (size_t)wid * D + gl * 4;
        float4 ev = {acc.x * inv, acc.y * inv, acc.z * inv, acc.w * inv};
        *(float4*)(Aout + o) = ev;
        if (wid < N_ITEMS) {
            float4 er = FIRST ? *(const float4*)(ERI + o) : *(const float4*)(ER + o);
            er.x += ev.x; er.y += ev.y; er.z += ev.z; er.w += ev.w;
            *(float4*)(ER + o) = er;
            if (gl == 0) snorm[wid] = nrm * icnt[wid];
        }
    }
}

// ==== per-user body: register-cached rows (KEEP=6/group) + online softmax ====
// Pass A gathers+caches first 6 rows per group (6 independent load chains);
// pass B consumes cached rows with zero memory traffic; tail edges re-gather.
template <bool FIRST>
__device__ __forceinline__ void user_hop_body(
        int wid, const float* __restrict__ E, const float* __restrict__ snorm,
        const int* __restrict__ rowstart, const int* __restrict__ cols,
        const float* __restrict__ vals, float* __restrict__ UR,
        const float* __restrict__ URI, f16* __restrict__ XHu) {
    int lane = threadIdx.x & 63;
    int g = lane >> 4, gl = lane & 15;
    if (wid >= N_USERS) return;
    int s = rowstart[wid], t = rowstart[wid + 1];

    // ---- pass A: cached prologue (static names; rule #20) ----
    float4 mean = {0.f, 0.f, 0.f, 0.f};
    #define UH_LOAD(K)                                                          \
        const int eP##K = s + g + 4 * K;                                        \
        const bool ok##K = eP##K < t;                                           \
        const int cP##K = ok##K ? cols[eP##K] : 0;                              \
        const float snP##K = ok##K ? snorm[cP##K] : 0.f;                        \
        const float vP##K = ok##K ? vals[eP##K] : 0.f;                          \
        float4 rP##K = {0.f, 0.f, 0.f, 0.f};                                    \
        if (ok##K) rP##K = *(const float4*)(E + (size_t)cP##K * D + gl * 4);
    UH_LOAD(0) UH_LOAD(1) UH_LOAD(2) UH_LOAD(3) UH_LOAD(4) UH_LOAD(5)
    #undef UH_LOAD
    #define UH_MEAN(K) {                                                        \
        float w = vP##K * snP##K;                                               \
        mean.x += w * rP##K.x; mean.y += w * rP##K.y;                           \
        mean.z += w * rP##K.z; mean.w += w * rP##K.w; }
    UH_MEAN(0) UH_MEAN(1) UH_MEAN(2) UH_MEAN(3) UH_MEAN(4) UH_MEAN(5)
    #undef UH_MEAN
    // dynamic tail (rare: only groups with >6 edges)
    for (int e = s + g + 24; e < t; e += 4) {
        int c = cols[e];
        float w = vals[e] * snorm[c];
        float4 r = *(const float4*)(E + (size_t)c * D + gl * 4);
        mean.x += w * r.x; mean.y += w * r.y;
        mean.z += w * r.z; mean.w += w * r.w;
    }
    mean.x += __shfl_xor(mean.x, 16, 64); mean.x += __shfl_xor(mean.x, 32, 64);
    mean.y += __shfl_xor(mean.y, 16, 64); mean.y += __shfl_xor(mean.y, 32, 64);
    mean.z += __shfl_xor(mean.z, 16, 64); mean.z += __shfl_xor(mean.z, 32, 64);
    mean.w += __shfl_xor(mean.w, 16, 64); mean.w += __shfl_xor(mean.w, 32, 64);

    // ---- pass B: online softmax from cached rows, then re-gather tail ----
    float m = -INFINITY, denom = 0.f;
    float4 acc = {0.f, 0.f, 0.f, 0.f};
    #define UH_SM(K) if (ok##K) {                                               \
        float4 il = {snP##K * rP##K.x, snP##K * rP##K.y,                        \
                     snP##K * rP##K.z, snP##K * rP##K.w};                       \
        float dx = il.x - mean.x + EPS_PD;                                      \
        float dy = il.y - mean.y + EPS_PD;                                      \
        float dz = il.z - mean.z + EPS_PD;                                      \
        float dw = il.w - mean.w + EPS_PD;                                      \
        float ssl = dx * dx + dy * dy + dz * dz + dw * dw;                      \
        ssl += __shfl_xor(ssl, 1, 64); ssl += __shfl_xor(ssl, 2, 64);           \
        ssl += __shfl_xor(ssl, 4, 64); ssl += __shfl_xor(ssl, 8, 64);           \
        float sc = sqrtf(ssl) * INV_TEMP;                                       \
        float m_new = fmaxf(m, sc);                                             \
        float scale = __expf(m - m_new);                                        \
        float ex = __expf(sc - m_new);                                          \
        denom = denom * scale + ex;                                             \
        acc.x = acc.x * scale + ex * il.x;                                      \
        acc.y = acc.y * scale + ex * il.y;                                      \
        acc.z = acc.z * scale + ex * il.z;                                      \
        acc.w = acc.w * scale + ex * il.w;                                      \
        m = m_new; }
    UH_SM(0) UH_SM(1) UH_SM(2) UH_SM(3) UH_SM(4) UH_SM(5)
    #undef UH_SM
    for (int e = s + g + 24; e < t; e += 4) {
        int c = cols[e];
        float sn = snorm[c];
        float4 r = *(const float4*)(E + (size_t)c * D + gl * 4);
        float4 il = {sn * r.x, sn * r.y, sn * r.z, sn * r.w};
        float dx = il.x - mean.x + EPS_PD;
        float dy = il.y - mean.y + EPS_PD;
        float dz = il.z - mean.z + EPS_PD;
        float dw = il.w - mean.w + EPS_PD;
        float ssl = dx * dx + dy * dy + dz * dz + dw * dw;
        ssl += __shfl_xor(ssl, 1, 64); ssl += __shfl_xor(ssl, 2, 64);
        ssl += __shfl_xor(ssl, 4, 64); ssl += __shfl_xor(ssl, 8, 64);
        float sc = sqrtf(ssl) * INV_TEMP;
        float m_new = fmaxf(m, sc);
        float scale = __expf(m - m_new);
        float ex = __expf(sc - m_new);
        denom = denom * scale + ex;
        acc.x = acc.x * scale + ex * il.x;
        acc.y = acc.y * scale + ex * il.y;
        acc.z = acc.z * scale + ex * il.z;
        acc.w = acc.w * scale + ex * il.w;
        m = m_new;
    }
    // merge 4 group states
    float mg = fmaxf(m, __shfl_xor(m, 16, 64));
    mg = fmaxf(mg, __shfl_xor(mg, 32, 64));
    float scl = __expf(fmaxf(m - mg, -88.0f));   // fmax eats NaN from (-inf)-(-inf)
    denom *= scl;
    acc.x *= scl; acc.y *= scl; acc.z *= scl; acc.w *= scl;
    denom += __shfl_xor(denom, 16, 64); denom += __shfl_xor(denom, 32, 64);
    acc.x += __shfl_xor(acc.x, 16, 64); acc.x += __shfl_xor(acc.x, 32, 64);
    acc.y += __shfl_xor(acc.y, 16, 64); acc.y += __shfl_xor(acc.y, 32, 64);
    acc.z += __shfl_xor(acc.z, 16, 64); acc.z += __shfl_xor(acc.z, 32, 64);
    acc.w += __shfl_xor(acc.w, 16, 64); acc.w += __shfl_xor(acc.w, 32, 64);
    float invd = denom > 0.f ? 1.0f / denom : 0.f;
    acc.x *= invd; acc.y *= invd; acc.z *= invd; acc.w *= invd;
    float ss = acc.x * acc.x + acc.y * acc.y + acc.z * acc.z + acc.w * acc.w;
    ss += __shfl_xor(ss, 1, 64); ss += __shfl_xor(ss, 2, 64);
    ss += __shfl_xor(ss, 4, 64); ss += __shfl_xor(ss, 8, 64);
    float inv = 1.0f / fmaxf(sqrtf(ss), 1e-12f);
    if (g == 0) {
        size_t o = (size_t)wid * D + gl * 4;
        float4 u = FIRST ? *(const float4*)(URI + o) : *(const float4*)(UR + o);
        u.x += acc.x * inv; u.y += acc.y * inv; u.z += acc.z * inv; u.w += acc.w * inv;
        *(float4*)(UR + o) = u;
        if (XHu) st_h4(XHu + o, u);
    }
}

// ==== hop-1 over all entities ====
__global__ void kg1_kernel(const int* __restrict__ rowptr, const int* __restrict__ tails,
                           const float* __restrict__ icnt, const float* __restrict__ Ain,
                           float* __restrict__ A1, float* __restrict__ ER,
                           const float* __restrict__ ERI, float* __restrict__ sn1) {
    int wid = (blockIdx.x * blockDim.x + threadIdx.x) >> 6;
    kg_hop_body<true>(wid, rowptr, tails, icnt, Ain, A1, ER, ERI, sn1, N_ENTITIES);
}

// ==== mid: user_hop1 (blocks < UH_GRID) || kg_hop2 (rest) — both read A1 ====
__global__ void mid_kernel(const float* __restrict__ A1, const float* __restrict__ sn1,
                           const int* __restrict__ rowstart, const int* __restrict__ cols,
                           const float* __restrict__ vals, float* __restrict__ UR,
                           const float* __restrict__ URI, const int* __restrict__ rowptr,
                           const int* __restrict__ tails, const float* __restrict__ icnt,
                           float* __restrict__ A0I, float* __restrict__ ER,
                           float* __restrict__ sn2) {
    if (blockIdx.x < UH_GRID) {
        int wid = (blockIdx.x * blockDim.x + threadIdx.x) >> 6;
        user_hop_body<true>(wid, A1, sn1, rowstart, cols, vals, UR, URI, nullptr);
    } else {
        int wid = (((blockIdx.x - UH_GRID) * blockDim.x) + threadIdx.x) >> 6;
        kg_hop_body<false>(wid, rowptr, tails, icnt, A1, A0I, ER, nullptr, sn2, N_ITEMS);
    }
}

// ==== fin: user_hop2 (+XH user part) || ER -> XH items cvt ====
__global__ void fin_kernel(const float* __restrict__ A0I, const float* __restrict__ sn2,
                           const int* __restrict__ rowstart, const int* __restrict__ cols,
                           const float* __restrict__ vals, float* __restrict__ UR,
                           f16* __restrict__ XH, const float* __restrict__ ER) {
    if (blockIdx.x < UH_GRID) {
        int wid = (blockIdx.x * blockDim.x + threadIdx.x) >> 6;
        user_hop_body<false>(wid, A0I, sn2, rowstart, cols, vals, UR, nullptr, XH);
    } else {
        int i = (blockIdx.x - UH_GRID) * blockDim.x + threadIdx.x;
        if (i < (N_ITEMS * D) / 4)
            st_h4(XH + (size_t)N_USERS * D + (size_t)i * 4,
                  *(const float4*)(ER + (size_t)i * 4));
    }
}

// ==== adj gather SpMM over fp16 rows, 4-wide chunked; fp32 epilogues ====
__device__ __forceinline__ const float* xrow32(const float* U, const float* I, int c) {
    return (c < N_USERS) ? (U + (size_t)c * D) : (I + (size_t)(c - N_USERS) * D);
}

template <int MODE>
__global__ void adj_spmm(const int* __restrict__ rowptr, const int2* __restrict__ pair,
                         const f16* __restrict__ X, const float* __restrict__ XAU,
                         const float* __restrict__ XAI, f16* __restrict__ Y,
                         float* __restrict__ out) {
    int wid = (blockIdx.x * blockDim.x + threadIdx.x) >> 6;
    int lane = threadIdx.x & 63;
    int g = lane >> 4, gl = lane & 15;
    if (wid >= N_UI) return;
    int s = rowptr[wid], t = rowptr[wid + 1];
    float4 acc = {0.f, 0.f, 0.f, 0.f};
    for (int e = s + g; e < t; e += 16) {
        int e1 = e + 4, e2 = e + 8, e3 = e + 12;
        int2 p0 = pair[e];
        int2 p1 = (e1 < t) ? pair[e1] : make_int2(0, 0);
        int2 p2 = (e2 < t) ? pair[e2] : make_int2(0, 0);
        int2 p3 = (e3 < t) ? pair[e3] : make_int2(0, 0);
        float4 r0 = ld_h4(X + (size_t)p0.x * D + gl * 4);
        float4 r1 = {0.f, 0.f, 0.f, 0.f};
        float4 r2 = {0.f, 0.f, 0.f, 0.f};
        float4 r3 = {0.f, 0.f, 0.f, 0.f};
        if (e1 < t) r1 = ld_h4(X + (size_t)p1.x * D + gl * 4);
        if (e2 < t) r2 = ld_h4(X + (size_t)p2.x * D + gl * 4);
        if (e3 < t) r3 = ld_h4(X + (size_t)p3.x * D + gl * 4);
        float v0 = __int_as_float(p0.y), v1 = __int_as_float(p1.y);
        float v2 = __int_as_float(p2.y), v3 = __int_as_float(p3.y);
        acc.x += (v0 * r0.x + v1 * r1.x) + (v2 * r2.x + v3 * r3.x);
        acc.y += (v0 * r0.y + v1 * r1.y) + (v2 * r2.y + v3 * r3.y);
        acc.z += (v0 * r0.z + v1 * r1.z) + (v2 * r2.z + v3 * r3.z);
        acc.w += (v0 * r0.w + v1 * r1.w) + (v2 * r2.w + v3 * r3.w);
    }
    acc.x += __shfl_xor(acc.x, 16, 64); acc.x += __shfl_xor(acc.x, 32, 64);
    acc.y += __shfl_xor(acc.y, 16, 64); acc.y += __shfl_xor(acc.y, 32, 64);
    acc.z += __shfl_xor(acc.z, 16, 64); acc.z += __shfl_xor(acc.z, 32, 64);
    acc.w += __shfl_xor(acc.w, 16, 64); acc.w += __shfl_xor(acc.w, 32, 64);
    if (g == 0) {
        size_t o = (size_t)wid * D + gl * 4;
        if (MODE == 0) {
            st_h4(Y + o, acc);
            const float4 xa = *(const float4*)(xrow32(XAU, XAI, wid) + gl * 4);
            float4 ov = {xa.x + acc.x, xa.y + acc.y, xa.z + acc.z, xa.w + acc.w};
            *(float4*)(out + o) = ov;
        } else {
            float4 ov = *(const float4*)(out + o);
            ov.x = (ov.x + acc.x) * (1.0f / 3.0f);
            ov.y = (ov.y + acc.y) * (1.0f / 3.0f);
            ov.z = (ov.z + acc.z) * (1.0f / 3.0f);
            ov.w = (ov.w + acc.w) * (1.0f / 3.0f);
            *(float4*)(out + o) = ov;
        }
    }
}

extern "C" void kernel_launch(void* const* d_in, const int* in_sizes, int n_in,
                              void* d_out, int out_size, void* d_ws, size_t ws_size,
                              hipStream_t stream) {
    const float* all_embed     = (const float*)d_in[0];
    const float* interact_vals = (const float*)d_in[1];
    const float* adj_vals      = (const float*)d_in[2];
    const int*   edge_index    = (const int*)d_in[3];
    // d_in[4] = edge_type (unused)
    const int*   interact_rows = (const int*)d_in[5];
    const int*   interact_cols = (const int*)d_in[6];
    const int*   adj_rows      = (const int*)d_in[7];
    const int*   adj_cols      = (const int*)d_in[8];
    float* out = (float*)d_out;

    const size_t usrN = (size_t)N_USERS * D;      // 3,200,000
    const size_t itmN = (size_t)N_ITEMS * D;      // 1,920,000
    const size_t entN = (size_t)N_ENTITIES * D;   // 5,120,000

    float* cur = (float*)d_ws;
    float* UR  = cur; cur += usrN;                // u_res fp32 (KG_BIN overlays pre-hop)
    float* ER  = cur; cur += itmN;                // e_res items fp32
    float* A0I = cur; cur += itmN;                // hop-2 entity output, items only
    float* A1  = cur; cur += entN;                // hop-1 output (ADJ_RC pre / XH,X1H post)
    int* KG_TAIL = (int*)cur; cur += N_KG_EDGES;
    int2* ADJ_PAIR = (int2*)cur; cur += 2 * (size_t)N_ADJ;  // dedicated, 8B aligned
    float* ICNT   = cur; cur += N_ENTITIES;
    float* SNORM1 = cur; cur += N_ITEMS + 16;
    float* SNORM2 = cur; cur += N_ITEMS + 16;
    int* KG_ROWPTR  = (int*)cur;                   // N_ENTITIES+1 (+pad)
    int* ADJ_ROWPTR = KG_ROWPTR + N_ENTITIES + 2;  // N_UI+1 (+pad)
    int* BCNT_K     = ADJ_ROWPTR + N_UI + 2;       // NB  (BCNT_K/BCNT_A contiguous!)
    int* BCNT_A     = BCNT_K + NB;                 // NB
    int* BOFF_K     = BCNT_A + NB;                 // NB+1
    int* BOFF_A     = BOFF_K + NB + 1;             // NB+1
    int* BCUR_K     = BOFF_A + NB + 1;             // NB
    int* BCUR_A     = BCUR_K + NB;                 // NB
    int* ROWSTART   = BCUR_A + NB;                 // N_USERS+1

    // overlays (timeline-disjoint)
    int*  KG_BIN = (int*)UR;                       // binA..binC, before user_hop1 writes UR
    int2* ADJ_RC = (int2*)A1;                      // binA..binC, before kg1 writes A1
    f16*  XH  = (f16*)A1;                          // after mid (A1 dead post kg_hop2)
    f16*  X1H = XH + (size_t)N_UI * D;

    // ---- CSR builds (KG + adj fused stage-wise) ----
    hipMemsetAsync(BCNT_K, 0, 2 * NB * sizeof(int), stream);
    bhist_plus<<<2 * GRID_EP + 49, BIG, 0, stream>>>(edge_index, adj_rows, interact_rows,
                                                     BCNT_K, BCNT_A, ROWSTART);
    bscan_both<<<2, 256, 0, stream>>>(BCNT_K, BOFF_K, BCUR_K, BCNT_A, BOFF_A, BCUR_A);
    binA_both<<<2 * GRID_EP, BIG, 0, stream>>>(edge_index, BCUR_K, KG_BIN, adj_rows,
                                               adj_cols, adj_vals, BCUR_A, ADJ_RC);
    binC_both<<<2 * NB, 256, 0, stream>>>(BOFF_K, KG_BIN, KG_TAIL, KG_ROWPTR, ICNT,
                                          BOFF_A, ADJ_RC, ADJ_PAIR, ADJ_ROWPTR);

    // ---- KG hops: kg1 -> (user1 || kg2) -> (user2 || cvt-items) ----
    kg1_kernel<<<N_ENTITIES / 4, 256, 0, stream>>>(KG_ROWPTR, KG_TAIL, ICNT,
                                                   all_embed + usrN, A1, ER,
                                                   all_embed + usrN, SNORM1);
    mid_kernel<<<UH_GRID + KG2_GRID, 256, 0, stream>>>(A1, SNORM1, ROWSTART,
                                                       interact_cols, interact_vals,
                                                       UR, all_embed, KG_ROWPTR, KG_TAIL,
                                                       ICNT, A0I, ER, SNORM2);
    fin_kernel<<<UH_GRID + CVT_GRID, 256, 0, stream>>>(A0I, SNORM2, ROWSTART,
                                                       interact_cols, interact_vals,
                                                       UR, XH, ER);

    // ---- LGCN: x1 = adj@x -> X1H(fp16), out = x + x1; out = (out + adj@x1)/3 ----
    adj_spmm<0><<<N_UI / 4, 256, 0, stream>>>(ADJ_ROWPTR, ADJ_PAIR, XH, UR, ER, X1H, out);
    adj_spmm<1><<<N_UI / 4, 256, 0, stream>>>(ADJ_ROWPTR, ADJ_PAIR, X1H, nullptr, nullptr,
                                              nullptr, out);
}